// Round 10
// baseline (359.554 us; speedup 1.0000x reference)
//
#include <hip/hip_runtime.h>

typedef unsigned short u16;
typedef unsigned int   u32;
typedef __attribute__((ext_vector_type(4))) float f32x4;
typedef __attribute__((ext_vector_type(8))) short short8;

#define MODEL_DIM 1024
#define SEQ 2048
#define BATCH 4
#define NHEAD 16
#define HDIM 64
#define MTOT (BATCH*SEQ)                       /* 8192 */
#define ELEMS ((size_t)MTOT*MODEL_DIM)         /* 8388608 */

__device__ __forceinline__ u16 f2bf(float f) {
    u32 u = __float_as_uint(f);
    u = (u + 0x7fffu + ((u >> 16) & 1u)) >> 16;   // RNE
    return (u16)u;
}
__device__ __forceinline__ u32 pack2(float a, float b) {
    return (u32)f2bf(a) | ((u32)f2bf(b) << 16);
}
// packed RNE f32x2 -> bf16x2 (1 instr; no builtin on gfx950, T12 recipe)
__device__ __forceinline__ u32 cvtpk(float lo, float hi) {
    u32 r;
    asm("v_cvt_pk_bf16_f32 %0, %1, %2" : "=v"(r) : "v"(lo), "v"(hi));
    return r;
}
// raw 2^x (v_exp_f32); softmax runs in log2 domain (log2e folded into Q scale)
__device__ __forceinline__ float exp2a(float x) {
    float r;
    asm("v_exp_f32 %0, %1" : "=v"(r) : "v"(x));
    return r;
}

// async global->LDS 16B: wave-uniform LDS base + lane*16 (m97 pattern)
#define GLOAD16(g, l) __builtin_amdgcn_global_load_lds(                        \
        (const __attribute__((address_space(1))) unsigned int*)(g),            \
        (__attribute__((address_space(3))) unsigned int*)(l), 16, 0, 0)

// ------------------------- prep: cast X -> bf16  +  W[k][n] fp32 -> Wt[n][k] bf16
// flat grid: blocks [0, 8192) cast; blocks [8192, 12288) transpose W.
__global__ __launch_bounds__(256) void prep_k(const float* __restrict__ X,
                                              u16* __restrict__ Xb,
                                              const float* __restrict__ Wq,
                                              const float* __restrict__ Wk,
                                              const float* __restrict__ Wv,
                                              const float* __restrict__ Wo,
                                              u16* __restrict__ Wt) {
    const int bid = blockIdx.x, t = threadIdx.x;
    if (bid < 8192) {
        size_t i = ((size_t)bid * 256 + t) * 4;
        float4 v = *(const float4*)(X + i);
        uint2 o; o.x = pack2(v.x, v.y); o.y = pack2(v.z, v.w);
        *(uint2*)(Xb + i) = o;
        return;
    }
    __shared__ float tile[32][33];
    const int bid2 = bid - 8192;
    const int z = bid2 >> 10, rem = bid2 & 1023;
    const int by = rem >> 5, bx = rem & 31;
    const float* W = (z == 0) ? Wq : (z == 1) ? Wk : (z == 2) ? Wv : Wo;
    const int k0 = by * 32, n0 = bx * 32;
    const int x = t & 31, y = t >> 5;                   // 32 x 8
    for (int i = 0; i < 4; ++i)
        tile[y + i * 8][x] = W[(size_t)(k0 + y + i * 8) * MODEL_DIM + n0 + x];
    __syncthreads();
    u16* out = Wt + ((size_t)z << 20);
    for (int i = 0; i < 4; ++i)
        out[(size_t)(n0 + y + i * 8) * MODEL_DIM + k0 + x] = f2bf(tile[x][y + i * 8]);
}

// ------------------------------------------------ QKV GEMM 256x256, 8-phase
// T2+T3+T4+T5 template (m201 structure): 512 thr = 8 waves (2M x 4N), BK=64,
// double-buffered 128KB LDS, raw barriers, counted vmcnt (never drained in
// loop), (row&7)<<4 XOR swizzle applied involutively on gload-source + ds_read.
// Wave-ownership staging: each wave stages exactly the A-half (wr) and B-half
// (wc>>1) it consumes -> its own vmcnt covers its reads; barrier publishes.
// Epilogues fused: RoPE for Q/K (Q pre-scaled 0.125*log2e), direct VT32 pack.
__global__ __launch_bounds__(512, 2) void gemm256qkv_k(
        const u16* __restrict__ A, const u16* __restrict__ Wt,
        u16* __restrict__ Qb, u16* __restrict__ Kb, u32* __restrict__ VT,
        const float* __restrict__ bq, const float* __restrict__ bk,
        const float* __restrict__ bv) {
    __shared__ __align__(16) u16 Ls[65536];        // 128KB: 2 buf x (A 32K + B 32K)
    const int tid  = threadIdx.x;
    const int wv   = tid >> 6, lane = tid & 63;
    const int l15  = lane & 15, quad = lane >> 4;
    const int wr = wv >> 2, wc = wv & 3;           // wave = (M-half, N-quarter)
    const int bh = wc >> 1;                        // B-half this wave consumes
    const int sb = wr * 2 + (wc & 1);              // sibling idx among B stagers
    const int m0 = blockIdx.x * 256;
    const int region = blockIdx.y >> 2;            // 0=Q 1=K 2=V
    const int n0loc = (blockIdx.y & 3) * 256;

    const u16* Ag = A + (size_t)m0 * MODEL_DIM;
    const u16* Bg = Wt + ((size_t)region << 20) + (size_t)n0loc * MODEL_DIM;

    f32x4 acc[8][4] = {};

// stage A-chunk q + B-chunk q of K-tile kt into buffer d (2 gloads/thread).
// LDS dest linear; global source pre-swizzled with the involution
// f(X) = X ^ (((X>>7)&7)<<4)  (row&7 XOR on 16B col slots).
#define STAGE2(kt, d, q) do {                                                  \
    const int kk0_ = (kt) * 64;                                                \
    { int L_ = ((q) * 256 + wc * 64 + lane) * 16;                              \
      int P_ = L_ ^ (((L_ >> 7) & 7) << 4);                                    \
      GLOAD16(Ag + (size_t)(wr * 128 + (P_ >> 7)) * MODEL_DIM + kk0_           \
                 + ((P_ & 127) >> 1),                                          \
              &Ls[(d) * 32768 + wr * 8192 + (L_ >> 1)]); }                     \
    { int L_ = ((q) * 256 + sb * 64 + lane) * 16;                              \
      int P_ = L_ ^ (((L_ >> 7) & 7) << 4);                                    \
      GLOAD16(Bg + (size_t)(bh * 128 + (P_ >> 7)) * MODEL_DIM + kk0_           \
                 + ((P_ & 127) >> 1),                                          \
              &Ls[(d) * 32768 + 16384 + bh * 8192 + (L_ >> 1)]); }             \
} while (0)

#define LDA8(mf, ks) ({                                                        \
    int P_ = ((mf) * 16 + l15) * 128 + ((ks) * 4 + quad) * 16;                 \
    int L_ = P_ ^ (((P_ >> 7) & 7) << 4);                                      \
    *(const short8*)(ab + (L_ >> 1)); })
#define LDB8(nf, ks) ({                                                        \
    int P_ = ((wc & 1) * 64 + (nf) * 16 + l15) * 128 + ((ks) * 4 + quad) * 16; \
    int L_ = P_ ^ (((P_ >> 7) & 7) << 4);                                      \
    *(const short8*)(bb2 + (L_ >> 1)); })

#define PHASE_MFMA(MH)                                                         \
    __builtin_amdgcn_s_setprio(1);                                             \
    _Pragma("unroll")                                                          \
    for (int j2 = 0; j2 < 4; ++j2)                                             \
        _Pragma("unroll")                                                      \
        for (int nf2 = 0; nf2 < 4; ++nf2)                                      \
            acc[(MH) * 4 + j2][nf2] = __builtin_amdgcn_mfma_f32_16x16x32_bf16( \
                af[j2], bf[nf2], acc[(MH) * 4 + j2][nf2], 0, 0, 0);            \
    __builtin_amdgcn_s_setprio(0);

    // prologue: stage tile 0 into buf 0 (8 gloads/thread)
    STAGE2(0, 0, 0); STAGE2(0, 0, 1); STAGE2(0, 0, 2); STAGE2(0, 0, 3);

    for (int t = 0; t < 16; ++t) {
        const int pp2 = t & 1;
        const u16* ab  = &Ls[pp2 * 32768 + wr * 8192];
        const u16* bb2 = &Ls[pp2 * 32768 + 16384 + bh * 8192];
        const int dn = pp2 ^ 1;
        const bool more = (t + 1) < 16;
        short8 af[4], bf[4];
        // ---- phase 0 (ks=0, mh=0): boundary — counted vmcnt, then publish
        if (more) STAGE2(t + 1, dn, 0);
        if (more) asm volatile("s_waitcnt vmcnt(2)" ::: "memory");
        else      asm volatile("s_waitcnt vmcnt(0)" ::: "memory");
        __builtin_amdgcn_s_barrier();
        __builtin_amdgcn_sched_barrier(0);
        #pragma unroll
        for (int nf = 0; nf < 4; ++nf) bf[nf] = LDB8(nf, 0);
        #pragma unroll
        for (int j = 0; j < 4; ++j) af[j] = LDA8(j, 0);
        PHASE_MFMA(0)
        __builtin_amdgcn_s_barrier();
        // ---- phase 1 (ks=0, mh=1)
        #pragma unroll
        for (int j = 0; j < 4; ++j) af[j] = LDA8(4 + j, 0);
        if (more) STAGE2(t + 1, dn, 1);
        __builtin_amdgcn_s_barrier();
        __builtin_amdgcn_sched_barrier(0);
        PHASE_MFMA(1)
        __builtin_amdgcn_s_barrier();
        // ---- phase 2 (ks=1, mh=0)
        #pragma unroll
        for (int nf = 0; nf < 4; ++nf) bf[nf] = LDB8(nf, 1);
        #pragma unroll
        for (int j = 0; j < 4; ++j) af[j] = LDA8(j, 1);
        if (more) STAGE2(t + 1, dn, 2);
        __builtin_amdgcn_s_barrier();
        __builtin_amdgcn_sched_barrier(0);
        PHASE_MFMA(0)
        __builtin_amdgcn_s_barrier();
        // ---- phase 3 (ks=1, mh=1)
        #pragma unroll
        for (int j = 0; j < 4; ++j) af[j] = LDA8(4 + j, 1);
        if (more) STAGE2(t + 1, dn, 3);
        __builtin_amdgcn_s_barrier();
        __builtin_amdgcn_sched_barrier(0);
        PHASE_MFMA(1)
        __builtin_amdgcn_s_barrier();
    }

    // ------------- epilogue: C/D layout per frag: col=l15, row=quad*4+r
    if (region < 2) {
        const float* bias = region ? bk : bq;
        u16* dst = region ? Kb : Qb;
        const float qsc = region ? 1.0f : 0.125f * 1.44269504f;
        const float cfr = -0.017989922f;               // -ln(10000)/512
        float invf[4];
        #pragma unroll
        for (int nf = 0; nf < 4; ++nf) {
            int c = n0loc + wc * 64 + nf * 16 + l15;
            invf[nf] = __expf((float)(c >> 1) * cfr);
        }
        const float sgn = (l15 & 1) ? 1.0f : -1.0f;    // even: x1*cs - x2*sn
        for (int mf = 0; mf < 8; ++mf)
            for (int r = 0; r < 4; ++r) {
                size_t rowg = (size_t)(m0 + wr * 128 + mf * 16 + quad * 4 + r);
                float fs = (float)(int)(rowg & 2047);
                #pragma unroll
                for (int nf = 0; nf < 4; ++nf) {
                    int c = n0loc + wc * 64 + nf * 16 + l15;
                    float v = acc[mf][nf][r] + bias[c];
                    float mate = __shfl_xor(v, 1, 64);
                    float sn, cs;
                    __sincosf(fs * invf[nf], &sn, &cs);
                    float o = (v * cs + sgn * mate * sn) * qsc;
                    dst[rowg * MODEL_DIM + c] = f2bf(o);
                }
            }
    } else {
        // V: pack + store V^T (VT32) directly from acc (R9-proven pattern)
        const int b_ = m0 >> 11;
        const int s0 = m0 & 2047;
        #pragma unroll
        for (int nf = 0; nf < 4; ++nf) {
            int c = n0loc + wc * 64 + nf * 16 + l15;
            float bvc = bv[c];
            u32* vtrow = VT + (size_t)((b_ * NHEAD + (c >> 6)) * HDIM
                                       + (c & 63)) * (SEQ / 2);
            for (int mf = 0; mf < 8; ++mf) {
                int sb2 = s0 + wr * 128 + mf * 16 + quad * 4;
                uint2 w;
                w.x = cvtpk(acc[mf][nf][0] + bvc, acc[mf][nf][1] + bvc);
                w.y = cvtpk(acc[mf][nf][2] + bvc, acc[mf][nf][3] + bvc);
                *(uint2*)(vtrow + (sb2 >> 1)) = w;
            }
        }
    }
#undef STAGE2
#undef LDA8
#undef LDB8
#undef PHASE_MFMA
}

// ----------------------------------------------------------------- GEMM 128x128
// m97 structure (proven): used for the O-projection (MODE 1 path only).
__global__ __launch_bounds__(256) void gemm128o_k(
        const u16* __restrict__ A, const u16* __restrict__ Wt,
        float* __restrict__ outO, const float* __restrict__ bo) {
    __shared__ __align__(16) u16 As[128 * 32];
    __shared__ __align__(16) u16 Bs[128 * 32];
    const int tid  = threadIdx.x;
    const int wave = tid >> 6, lane = tid & 63;
    const int l15  = lane & 15, quad = lane >> 4;
    const int wm = (wave & 1) * 64, wn = (wave >> 1) * 64;
    const int m0 = blockIdx.x * 128;
    const int n0 = blockIdx.y * 128;

    const u16* bbase = Wt + ((size_t)3 << 20) + (size_t)n0 * MODEL_DIM;
    const u16* abase = A + (size_t)m0 * MODEL_DIM;

    f32x4 acc[4][4] = {};
    const int r0 = tid >> 2, kc0 = (tid & 3) * 8;
    const u16* ga = abase + (size_t)r0 * MODEL_DIM + kc0;
    const u16* gb = bbase + (size_t)r0 * MODEL_DIM + kc0;
    u16* la0 = &As[tid * 8];
    u16* la1 = &As[2048 + tid * 8];
    u16* lb0 = &Bs[tid * 8];
    u16* lb1 = &Bs[2048 + tid * 8];

    for (int k0 = 0; k0 < MODEL_DIM; k0 += 32) {
        GLOAD16(ga + k0, la0);
        GLOAD16(ga + (size_t)64 * MODEL_DIM + k0, la1);
        GLOAD16(gb + k0, lb0);
        GLOAD16(gb + (size_t)64 * MODEL_DIM + k0, lb1);
        __syncthreads();
        short8 af[4], bf[4];
        for (int i = 0; i < 4; ++i)
            af[i] = *(const short8*)(&As[(wm + i * 16 + l15) * 32 + quad * 8]);
        for (int i = 0; i < 4; ++i)
            bf[i] = *(const short8*)(&Bs[(wn + i * 16 + l15) * 32 + quad * 8]);
        for (int mi = 0; mi < 4; ++mi)
            for (int ni = 0; ni < 4; ++ni)
                acc[mi][ni] = __builtin_amdgcn_mfma_f32_16x16x32_bf16(
                                  af[mi], bf[ni], acc[mi][ni], 0, 0, 0);
        __syncthreads();
    }

    for (int mi = 0; mi < 4; ++mi)
        for (int r = 0; r < 4; ++r) {
            size_t rowg = (size_t)(m0 + wm + mi * 16 + quad * 4 + r);
            for (int ni = 0; ni < 4; ++ni) {
                int colg = n0 + wn + ni * 16 + l15;
                outO[rowg * MODEL_DIM + colg] = acc[mi][ni][r] + bo[colg];
            }
        }
}

// ------------------------------------------------------- flash attention (causal)
// grid (8,16,4); 256 thr = 4 waves; wave owns 32 q-rows of the active q-tile.
// Causal pair-balancing; T14 dbuf pipeline; T13 defer-max; T5 setprio; exp2.
__global__ __launch_bounds__(256, 2) void attn_k(const u16* __restrict__ Qb,
                                                 const u16* __restrict__ Kb,
                                                 const u32* __restrict__ VT32,
                                                 u16* __restrict__ Ob) {
    __shared__ __align__(16) u16 Ks[2][64 * 64];   // [key][dim], chunk-XOR swizzle
    __shared__ __align__(16) u16 Vs[2][64 * 64];   // [d][key],   chunk-XOR swizzle
    __shared__ __align__(16) u16 Pl[4 * 32 * 72];  // per-wave P^T [q][key], pad 8
    const int tid  = threadIdx.x;
    const int wave = tid >> 6, lane = tid & 63;
    const int l15  = lane & 15, quad = lane >> 4;
    const int j = blockIdx.x;                      // 0..7 pair index
    const int h = blockIdx.y, b = blockIdx.z;
    u16* pw = &Pl[wave * 32 * 72];

    const int key0 = tid >> 3;                     // 0..31
    const int c8   = (tid & 7) * 8;                // u16 units
    const int c4   = (tid & 7) * 4;                // u32 units (VT rows)
    const int lko  = key0 * 64 + (((tid & 7) ^ (key0 & 7)) * 8);   // LDS dst
    const u16* kgp = Kb + (size_t)(b * SEQ) * MODEL_DIM + h * HDIM;
    const u32* vgp = VT32 + (size_t)((b * NHEAD + h) * HDIM) * (SEQ / 2);

    int bufc = 0;                                  // buffer parity, spans passes
    for (int pp = 0; pp < 2; ++pp) {
        const int qt = pp ? j : 15 - j;            // heavy tile first
        const int q0 = qt * 128;
        const int qbase = q0 + wave * 32;

        short8 qfr[2][2];
        for (int qf = 0; qf < 2; ++qf)
            for (int ks = 0; ks < 2; ++ks)
                qfr[qf][ks] = *(const short8*)(Qb
                    + (size_t)(b * SEQ + qbase + qf * 16 + l15) * MODEL_DIM
                    + h * HDIM + ks * 32 + quad * 8);

        float m_i[2] = {-1e30f, -1e30f}, l_i[2] = {0.f, 0.f};
        f32x4 o_acc[4][2] = {};                    // [dt][qf]

        const int nkt = (q0 + 128) >> 6;
        uint4 kr0 = *(const uint4*)(kgp + (size_t)key0 * MODEL_DIM + c8);
        uint4 kr1 = *(const uint4*)(kgp + (size_t)(key0 + 32) * MODEL_DIM + c8);
        uint4 vr0 = *(const uint4*)(vgp + (size_t)key0 * (SEQ / 2) + c4);
        uint4 vr1 = *(const uint4*)(vgp + (size_t)(key0 + 32) * (SEQ / 2) + c4);

        for (int kt = 0; kt < nkt; ++kt) {
            const int k0 = kt * 64;
            u16* ksb = Ks[bufc];
            u16* vsb = Vs[bufc];
            *(uint4*)(&ksb[lko])        = kr0;
            *(uint4*)(&ksb[lko + 2048]) = kr1;
            *(uint4*)(&vsb[lko])        = vr0;
            *(uint4*)(&vsb[lko + 2048]) = vr1;
            __syncthreads();

            if (kt + 1 < nkt) {
                const int kn = k0 + 64;
                kr0 = *(const uint4*)(kgp + (size_t)(kn + key0) * MODEL_DIM + c8);
                kr1 = *(const uint4*)(kgp + (size_t)(kn + key0 + 32) * MODEL_DIM + c8);
                vr0 = *(const uint4*)(vgp + (size_t)key0 * (SEQ / 2) + (kn >> 1) + c4);
                vr1 = *(const uint4*)(vgp + (size_t)(key0 + 32) * (SEQ / 2)
                                      + (kn >> 1) + c4);
            }

            if (k0 <= qbase + 31) {
                f32x4 s[4][2] = {};
                for (int ks = 0; ks < 2; ++ks) {
                    short8 kfr[4];
                    for (int kf = 0; kf < 4; ++kf)
                        kfr[kf] = *(const short8*)(&ksb[(kf * 16 + l15) * 64
                                      + (((ks * 4 + quad) ^ (l15 & 7)) * 8)]);
                    __builtin_amdgcn_s_setprio(1);
                    for (int kf = 0; kf < 4; ++kf)
                        for (int qf = 0; qf < 2; ++qf)
                            s[kf][qf] = __builtin_amdgcn_mfma_f32_16x16x32_bf16(
                                            kfr[kf], qfr[qf][ks], s[kf][qf], 0, 0, 0);
                    __builtin_amdgcn_s_setprio(0);
                }
                for (int qf = 0; qf < 2; ++qf) {
                    int qg = qbase + qf * 16 + l15;
                    if (k0 + 63 > qbase + qf * 16) {
                        for (int kf = 0; kf < 4; ++kf)
                            for (int r = 0; r < 4; ++r)
                                if (k0 + kf * 16 + quad * 4 + r > qg)
                                    s[kf][qf][r] = -1e30f;
                    }
                    float t0 = fmaxf(fmaxf(s[0][qf][0], s[0][qf][1]),
                                     fmaxf(s[0][qf][2], s[0][qf][3]));
                    float t1 = fmaxf(fmaxf(s[1][qf][0], s[1][qf][1]),
                                     fmaxf(s[1][qf][2], s[1][qf][3]));
                    float t2 = fmaxf(fmaxf(s[2][qf][0], s[2][qf][1]),
                                     fmaxf(s[2][qf][2], s[2][qf][3]));
                    float t3 = fmaxf(fmaxf(s[3][qf][0], s[3][qf][1]),
                                     fmaxf(s[3][qf][2], s[3][qf][3]));
                    float rmax = fmaxf(fmaxf(t0, t1), fmaxf(t2, t3));
                    rmax = fmaxf(rmax, __shfl_xor(rmax, 16, 64));
                    rmax = fmaxf(rmax, __shfl_xor(rmax, 32, 64));
                    if (!__all(rmax <= m_i[qf] + 8.0f)) {
                        float mn = fmaxf(m_i[qf], rmax);
                        float alpha = exp2a(m_i[qf] - mn);
                        m_i[qf] = mn;
                        l_i[qf] *= alpha;
                        for (int dt = 0; dt < 4; ++dt)
                            for (int r = 0; r < 4; ++r) o_acc[dt][qf][r] *= alpha;
                    }
                    float mref = m_i[qf];
                    float psum = 0.f;
                    for (int kf = 0; kf < 4; ++kf)
                        for (int r = 0; r < 4; ++r) {
                            float p = exp2a(s[kf][qf][r] - mref);
                            s[kf][qf][r] = p;
                            psum += p;
                        }
                    psum += __shfl_xor(psum, 16, 64);
                    psum += __shfl_xor(psum, 32, 64);
                    l_i[qf] += psum;
                    for (int kf = 0; kf < 4; ++kf) {
                        uint2 w;
                        w.x = cvtpk(s[kf][qf][0], s[kf][qf][1]);
                        w.y = cvtpk(s[kf][qf][2], s[kf][qf][3]);
                        *(uint2*)(&pw[(qf * 16 + l15) * 72 + kf * 16 + quad * 4]) = w;
                    }
                }
                for (int ks = 0; ks < 2; ++ks) {
                    short8 pfr[2], vfr[4];
                    for (int qf = 0; qf < 2; ++qf)
                        pfr[qf] = *(const short8*)(&pw[(qf * 16 + l15) * 72
                                                       + ks * 32 + quad * 8]);
                    for (int dt = 0; dt < 4; ++dt)
                        vfr[dt] = *(const short8*)(&vsb[(dt * 16 + l15) * 64
                                      + (((ks * 4 + quad) ^ (l15 & 7)) * 8)]);
                    __builtin_amdgcn_s_setprio(1);
                    for (int dt = 0; dt < 4; ++dt)
                        for (int qf = 0; qf < 2; ++qf)
                            o_acc[dt][qf] = __builtin_amdgcn_mfma_f32_16x16x32_bf16(
                                                vfr[dt], pfr[qf], o_acc[dt][qf], 0, 0, 0);
                    __builtin_amdgcn_s_setprio(0);
                }
            }
            bufc ^= 1;
        }

        for (int qf = 0; qf < 2; ++qf) {
            float rl = 1.f / l_i[qf];
            int q = qbase + qf * 16 + l15;
            for (int dt = 0; dt < 4; ++dt) {
                uint2 w;
                w.x = cvtpk(o_acc[dt][qf][0] * rl, o_acc[dt][qf][1] * rl);
                w.y = cvtpk(o_acc[dt][qf][2] * rl, o_acc[dt][qf][3] * rl);
                *(uint2*)(&Ob[(size_t)(b * SEQ + q) * MODEL_DIM
                              + h * HDIM + dt * 16 + quad * 4]) = w;
            }
        }
    }
}

// --------------------------------------------------------------------- launcher
extern "C" void kernel_launch(void* const* d_in, const int* in_sizes, int n_in,
                              void* d_out, int out_size, void* d_ws, size_t ws_size,
                              hipStream_t stream) {
    const float* X  = (const float*)d_in[0];
    const float* Wq = (const float*)d_in[1];
    const float* bq = (const float*)d_in[2];
    const float* Wk = (const float*)d_in[3];
    const float* bk = (const float*)d_in[4];
    const float* Wv = (const float*)d_in[5];
    const float* bv = (const float*)d_in[6];
    const float* Wo = (const float*)d_in[7];
    const float* bo = (const float*)d_in[8];
    float* out = (float*)d_out;

    // ws: [Xb/Ob 16.78M][Wt 8.39M][Qb 16.78M][Kb 16.78M][unused][VT 16.78M]
    char* ws = (char*)d_ws;
    u16* Xb   = (u16*)ws;                       // aliased by Ob after QKV GEMM
    u16* Ob   = (u16*)ws;
    u16* Wt   = (u16*)(ws + 16777216);
    u16* Qb   = (u16*)(ws + 25165824);
    u16* Kb   = (u16*)(ws + 41943040);
    u32* VT32 = (u32*)(ws + 75497472);

    prep_k<<<dim3(12288), dim3(256), 0, stream>>>(X, Xb, Wq, Wk, Wv, Wo, Wt);
    gemm256qkv_k<<<dim3(32, 12), dim3(512), 0, stream>>>(Xb, Wt, Qb, Kb, VT32,
                                                         bq, bk, bv);
    attn_k<<<dim3(8, 16, 4), dim3(256), 0, stream>>>(Qb, Kb, VT32, Ob);
    gemm128o_k<<<dim3(64, 8), dim3(256), 0, stream>>>(Ob, Wt, out, bo);
}

// Round 11
// 264.224 us; speedup vs baseline: 1.3608x; 1.3608x over previous
//
#include <hip/hip_runtime.h>

typedef unsigned short u16;
typedef unsigned int   u32;
typedef __attribute__((ext_vector_type(4))) float f32x4;
typedef __attribute__((ext_vector_type(8))) short short8;

#define MODEL_DIM 1024
#define SEQ 2048
#define BATCH 4
#define NHEAD 16
#define HDIM 64
#define MTOT (BATCH*SEQ)                       /* 8192 */
#define ELEMS ((size_t)MTOT*MODEL_DIM)         /* 8388608 */

__device__ __forceinline__ u16 f2bf(float f) {
    u32 u = __float_as_uint(f);
    u = (u + 0x7fffu + ((u >> 16) & 1u)) >> 16;   // RNE
    return (u16)u;
}
__device__ __forceinline__ u32 pack2(float a, float b) {
    return (u32)f2bf(a) | ((u32)f2bf(b) << 16);
}
// packed RNE f32x2 -> bf16x2 (1 instr; no builtin on gfx950, T12 recipe)
__device__ __forceinline__ u32 cvtpk(float lo, float hi) {
    u32 r;
    asm("v_cvt_pk_bf16_f32 %0, %1, %2" : "=v"(r) : "v"(lo), "v"(hi));
    return r;
}
// raw 2^x (v_exp_f32); softmax runs in log2 domain (log2e folded into Q scale)
__device__ __forceinline__ float exp2a(float x) {
    float r;
    asm("v_exp_f32 %0, %1" : "=v"(r) : "v"(x));
    return r;
}

// async global->LDS 16B: wave-uniform LDS base + lane*16 (m97 pattern)
#define GLOAD16(g, l) __builtin_amdgcn_global_load_lds(                        \
        (const __attribute__((address_space(1))) unsigned int*)(g),            \
        (__attribute__((address_space(3))) unsigned int*)(l), 16, 0, 0)

// ------------------------- prep: cast X -> bf16  +  W[k][n] fp32 -> Wt[n][k] bf16
// flat grid: blocks [0, 8192) cast; blocks [8192, 12288) transpose W.
__global__ __launch_bounds__(256) void prep_k(const float* __restrict__ X,
                                              u16* __restrict__ Xb,
                                              const float* __restrict__ Wq,
                                              const float* __restrict__ Wk,
                                              const float* __restrict__ Wv,
                                              const float* __restrict__ Wo,
                                              u16* __restrict__ Wt) {
    const int bid = blockIdx.x, t = threadIdx.x;
    if (bid < 8192) {
        size_t i = ((size_t)bid * 256 + t) * 4;
        float4 v = *(const float4*)(X + i);
        uint2 o; o.x = pack2(v.x, v.y); o.y = pack2(v.z, v.w);
        *(uint2*)(Xb + i) = o;
        return;
    }
    __shared__ float tile[32][33];
    const int bid2 = bid - 8192;
    const int z = bid2 >> 10, rem = bid2 & 1023;
    const int by = rem >> 5, bx = rem & 31;
    const float* W = (z == 0) ? Wq : (z == 1) ? Wk : (z == 2) ? Wv : Wo;
    const int k0 = by * 32, n0 = bx * 32;
    const int x = t & 31, y = t >> 5;                   // 32 x 8
    for (int i = 0; i < 4; ++i)
        tile[y + i * 8][x] = W[(size_t)(k0 + y + i * 8) * MODEL_DIM + n0 + x];
    __syncthreads();
    u16* out = Wt + ((size_t)z << 20);
    for (int i = 0; i < 4; ++i)
        out[(size_t)(n0 + y + i * 8) * MODEL_DIM + k0 + x] = f2bf(tile[x][y + i * 8]);
}

// ------------------------------------------------ QKV GEMM 256x256, 8-phase
// T2+T3+T4+T5 template (m201 structure): 512 thr = 8 waves (2M x 4N), BK=64,
// double-buffered 128KB LDS, raw barriers, counted vmcnt (never drained in
// loop), (row&7)<<4 XOR swizzle applied involutively on gload-source + ds_read.
// ROUND-11 FIX (rule #20): ALL loops touching acc are fully unrolled — R10's
// runtime-indexed epilogue loops put acc[8][4] in scratch for the whole kernel
// (VGPR 112, WRITE_SIZE 440MB, MfmaUtil 12%).
__global__ __launch_bounds__(512, 2) void gemm256qkv_k(
        const u16* __restrict__ A, const u16* __restrict__ Wt,
        u16* __restrict__ Qb, u16* __restrict__ Kb, u32* __restrict__ VT,
        const float* __restrict__ bq, const float* __restrict__ bk,
        const float* __restrict__ bv) {
    __shared__ __align__(16) u16 Ls[65536];        // 128KB: 2 buf x (A 32K + B 32K)
    const int tid  = threadIdx.x;
    const int wv   = tid >> 6, lane = tid & 63;
    const int l15  = lane & 15, quad = lane >> 4;
    const int wr = wv >> 2, wc = wv & 3;           // wave = (M-half, N-quarter)
    const int bh = wc >> 1;                        // B-half this wave consumes
    const int sb = wr * 2 + (wc & 1);              // sibling idx among B stagers
    const int m0 = blockIdx.x * 256;
    const int region = blockIdx.y >> 2;            // 0=Q 1=K 2=V
    const int n0loc = (blockIdx.y & 3) * 256;

    const u16* Ag = A + (size_t)m0 * MODEL_DIM;
    const u16* Bg = Wt + ((size_t)region << 20) + (size_t)n0loc * MODEL_DIM;

    f32x4 acc[8][4] = {};

// stage A-chunk q + B-chunk q of K-tile kt into buffer d (2 gloads/thread).
// LDS dest linear; global source pre-swizzled with the involution
// f(X) = X ^ (((X>>7)&7)<<4)  (row&7 XOR on 16B col slots).
#define STAGE2(kt, d, q) do {                                                  \
    const int kk0_ = (kt) * 64;                                                \
    { int L_ = ((q) * 256 + wc * 64 + lane) * 16;                              \
      int P_ = L_ ^ (((L_ >> 7) & 7) << 4);                                    \
      GLOAD16(Ag + (size_t)(wr * 128 + (P_ >> 7)) * MODEL_DIM + kk0_           \
                 + ((P_ & 127) >> 1),                                          \
              &Ls[(d) * 32768 + wr * 8192 + (L_ >> 1)]); }                     \
    { int L_ = ((q) * 256 + sb * 64 + lane) * 16;                              \
      int P_ = L_ ^ (((L_ >> 7) & 7) << 4);                                    \
      GLOAD16(Bg + (size_t)(bh * 128 + (P_ >> 7)) * MODEL_DIM + kk0_           \
                 + ((P_ & 127) >> 1),                                          \
              &Ls[(d) * 32768 + 16384 + bh * 8192 + (L_ >> 1)]); }             \
} while (0)

#define LDA8(mf, ks) ({                                                        \
    int P_ = ((mf) * 16 + l15) * 128 + ((ks) * 4 + quad) * 16;                 \
    int L_ = P_ ^ (((P_ >> 7) & 7) << 4);                                      \
    *(const short8*)(ab + (L_ >> 1)); })
#define LDB8(nf, ks) ({                                                        \
    int P_ = ((wc & 1) * 64 + (nf) * 16 + l15) * 128 + ((ks) * 4 + quad) * 16; \
    int L_ = P_ ^ (((P_ >> 7) & 7) << 4);                                      \
    *(const short8*)(bb2 + (L_ >> 1)); })

#define PHASE_MFMA(MH)                                                         \
    __builtin_amdgcn_s_setprio(1);                                             \
    _Pragma("unroll")                                                          \
    for (int j2 = 0; j2 < 4; ++j2)                                             \
        _Pragma("unroll")                                                      \
        for (int nf2 = 0; nf2 < 4; ++nf2)                                      \
            acc[(MH) * 4 + j2][nf2] = __builtin_amdgcn_mfma_f32_16x16x32_bf16( \
                af[j2], bf[nf2], acc[(MH) * 4 + j2][nf2], 0, 0, 0);            \
    __builtin_amdgcn_s_setprio(0);

    // prologue: stage tile 0 into buf 0 (8 gloads/thread)
    STAGE2(0, 0, 0); STAGE2(0, 0, 1); STAGE2(0, 0, 2); STAGE2(0, 0, 3);

    for (int t = 0; t < 16; ++t) {
        const int pp2 = t & 1;
        const u16* ab  = &Ls[pp2 * 32768 + wr * 8192];
        const u16* bb2 = &Ls[pp2 * 32768 + 16384 + bh * 8192];
        const int dn = pp2 ^ 1;
        const bool more = (t + 1) < 16;
        short8 af[4], bf[4];
        // ---- phase 0 (ks=0, mh=0): boundary — counted vmcnt, then publish
        if (more) STAGE2(t + 1, dn, 0);
        if (more) asm volatile("s_waitcnt vmcnt(2)" ::: "memory");
        else      asm volatile("s_waitcnt vmcnt(0)" ::: "memory");
        __builtin_amdgcn_s_barrier();
        __builtin_amdgcn_sched_barrier(0);
        #pragma unroll
        for (int nf = 0; nf < 4; ++nf) bf[nf] = LDB8(nf, 0);
        #pragma unroll
        for (int j = 0; j < 4; ++j) af[j] = LDA8(j, 0);
        PHASE_MFMA(0)
        __builtin_amdgcn_s_barrier();
        // ---- phase 1 (ks=0, mh=1)
        #pragma unroll
        for (int j = 0; j < 4; ++j) af[j] = LDA8(4 + j, 0);
        if (more) STAGE2(t + 1, dn, 1);
        __builtin_amdgcn_s_barrier();
        __builtin_amdgcn_sched_barrier(0);
        PHASE_MFMA(1)
        __builtin_amdgcn_s_barrier();
        // ---- phase 2 (ks=1, mh=0)
        #pragma unroll
        for (int nf = 0; nf < 4; ++nf) bf[nf] = LDB8(nf, 1);
        #pragma unroll
        for (int j = 0; j < 4; ++j) af[j] = LDA8(j, 1);
        if (more) STAGE2(t + 1, dn, 2);
        __builtin_amdgcn_s_barrier();
        __builtin_amdgcn_sched_barrier(0);
        PHASE_MFMA(0)
        __builtin_amdgcn_s_barrier();
        // ---- phase 3 (ks=1, mh=1)
        #pragma unroll
        for (int j = 0; j < 4; ++j) af[j] = LDA8(4 + j, 1);
        if (more) STAGE2(t + 1, dn, 3);
        __builtin_amdgcn_s_barrier();
        __builtin_amdgcn_sched_barrier(0);
        PHASE_MFMA(1)
        __builtin_amdgcn_s_barrier();
    }

    // ------------- epilogue: C/D layout per frag: col=l15, row=quad*4+r
    // ALL acc-indexing loops fully unrolled (rule #20) — compile-time indices.
    if (region < 2) {
        const float* bias = region ? bk : bq;
        u16* dst = region ? Kb : Qb;
        const float qsc = region ? 1.0f : 0.125f * 1.44269504f;
        const float cfr = -0.017989922f;               // -ln(10000)/512
        float invf[4];
        #pragma unroll
        for (int nf = 0; nf < 4; ++nf) {
            int c = n0loc + wc * 64 + nf * 16 + l15;
            invf[nf] = __expf((float)(c >> 1) * cfr);
        }
        const float sgn = (l15 & 1) ? 1.0f : -1.0f;    // even: x1*cs - x2*sn
        #pragma unroll
        for (int mf = 0; mf < 8; ++mf)
            #pragma unroll
            for (int r = 0; r < 4; ++r) {
                size_t rowg = (size_t)(m0 + wr * 128 + mf * 16 + quad * 4 + r);
                float fs = (float)(int)(rowg & 2047);
                #pragma unroll
                for (int nf = 0; nf < 4; ++nf) {
                    int c = n0loc + wc * 64 + nf * 16 + l15;
                    float v = acc[mf][nf][r] + bias[c];
                    float mate = __shfl_xor(v, 1, 64);
                    float sn, cs;
                    __sincosf(fs * invf[nf], &sn, &cs);
                    float o = (v * cs + sgn * mate * sn) * qsc;
                    dst[rowg * MODEL_DIM + c] = f2bf(o);
                }
            }
    } else {
        // V: pack + store V^T (VT32) directly from acc (R9-proven pattern)
        const int b_ = m0 >> 11;
        const int s0 = m0 & 2047;
        #pragma unroll
        for (int nf = 0; nf < 4; ++nf) {
            int c = n0loc + wc * 64 + nf * 16 + l15;
            float bvc = bv[c];
            u32* vtrow = VT + (size_t)((b_ * NHEAD + (c >> 6)) * HDIM
                                       + (c & 63)) * (SEQ / 2);
            #pragma unroll
            for (int mf = 0; mf < 8; ++mf) {
                int sb2 = s0 + wr * 128 + mf * 16 + quad * 4;
                uint2 w;
                w.x = cvtpk(acc[mf][nf][0] + bvc, acc[mf][nf][1] + bvc);
                w.y = cvtpk(acc[mf][nf][2] + bvc, acc[mf][nf][3] + bvc);
                *(uint2*)(vtrow + (sb2 >> 1)) = w;
            }
        }
    }
#undef STAGE2
#undef LDA8
#undef LDB8
#undef PHASE_MFMA
}

// ----------------------------------------------------------------- GEMM 128x128
// m97 structure (proven): used for the O-projection (MODE 1 path only).
__global__ __launch_bounds__(256) void gemm128o_k(
        const u16* __restrict__ A, const u16* __restrict__ Wt,
        float* __restrict__ outO, const float* __restrict__ bo) {
    __shared__ __align__(16) u16 As[128 * 32];
    __shared__ __align__(16) u16 Bs[128 * 32];
    const int tid  = threadIdx.x;
    const int wave = tid >> 6, lane = tid & 63;
    const int l15  = lane & 15, quad = lane >> 4;
    const int wm = (wave & 1) * 64, wn = (wave >> 1) * 64;
    const int m0 = blockIdx.x * 128;
    const int n0 = blockIdx.y * 128;

    const u16* bbase = Wt + ((size_t)3 << 20) + (size_t)n0 * MODEL_DIM;
    const u16* abase = A + (size_t)m0 * MODEL_DIM;

    f32x4 acc[4][4] = {};
    const int r0 = tid >> 2, kc0 = (tid & 3) * 8;
    const u16* ga = abase + (size_t)r0 * MODEL_DIM + kc0;
    const u16* gb = bbase + (size_t)r0 * MODEL_DIM + kc0;
    u16* la0 = &As[tid * 8];
    u16* la1 = &As[2048 + tid * 8];
    u16* lb0 = &Bs[tid * 8];
    u16* lb1 = &Bs[2048 + tid * 8];

    for (int k0 = 0; k0 < MODEL_DIM; k0 += 32) {
        GLOAD16(ga + k0, la0);
        GLOAD16(ga + (size_t)64 * MODEL_DIM + k0, la1);
        GLOAD16(gb + k0, lb0);
        GLOAD16(gb + (size_t)64 * MODEL_DIM + k0, lb1);
        __syncthreads();
        short8 af[4], bf[4];
        for (int i = 0; i < 4; ++i)
            af[i] = *(const short8*)(&As[(wm + i * 16 + l15) * 32 + quad * 8]);
        for (int i = 0; i < 4; ++i)
            bf[i] = *(const short8*)(&Bs[(wn + i * 16 + l15) * 32 + quad * 8]);
        for (int mi = 0; mi < 4; ++mi)
            for (int ni = 0; ni < 4; ++ni)
                acc[mi][ni] = __builtin_amdgcn_mfma_f32_16x16x32_bf16(
                                  af[mi], bf[ni], acc[mi][ni], 0, 0, 0);
        __syncthreads();
    }

    for (int mi = 0; mi < 4; ++mi)
        for (int r = 0; r < 4; ++r) {
            size_t rowg = (size_t)(m0 + wm + mi * 16 + quad * 4 + r);
            for (int ni = 0; ni < 4; ++ni) {
                int colg = n0 + wn + ni * 16 + l15;
                outO[rowg * MODEL_DIM + colg] = acc[mi][ni][r] + bo[colg];
            }
        }
}

// ------------------------------------------------------- flash attention (causal)
// grid (8,16,4); 256 thr = 4 waves; wave owns 32 q-rows of the active q-tile.
// Causal pair-balancing; T14 dbuf pipeline; T13 defer-max; T5 setprio; exp2.
__global__ __launch_bounds__(256, 2) void attn_k(const u16* __restrict__ Qb,
                                                 const u16* __restrict__ Kb,
                                                 const u32* __restrict__ VT32,
                                                 u16* __restrict__ Ob) {
    __shared__ __align__(16) u16 Ks[2][64 * 64];   // [key][dim], chunk-XOR swizzle
    __shared__ __align__(16) u16 Vs[2][64 * 64];   // [d][key],   chunk-XOR swizzle
    __shared__ __align__(16) u16 Pl[4 * 32 * 72];  // per-wave P^T [q][key], pad 8
    const int tid  = threadIdx.x;
    const int wave = tid >> 6, lane = tid & 63;
    const int l15  = lane & 15, quad = lane >> 4;
    const int j = blockIdx.x;                      // 0..7 pair index
    const int h = blockIdx.y, b = blockIdx.z;
    u16* pw = &Pl[wave * 32 * 72];

    const int key0 = tid >> 3;                     // 0..31
    const int c8   = (tid & 7) * 8;                // u16 units
    const int c4   = (tid & 7) * 4;                // u32 units (VT rows)
    const int lko  = key0 * 64 + (((tid & 7) ^ (key0 & 7)) * 8);   // LDS dst
    const u16* kgp = Kb + (size_t)(b * SEQ) * MODEL_DIM + h * HDIM;
    const u32* vgp = VT32 + (size_t)((b * NHEAD + h) * HDIM) * (SEQ / 2);

    int bufc = 0;                                  // buffer parity, spans passes
    for (int pp = 0; pp < 2; ++pp) {
        const int qt = pp ? j : 15 - j;            // heavy tile first
        const int q0 = qt * 128;
        const int qbase = q0 + wave * 32;

        short8 qfr[2][2];
        for (int qf = 0; qf < 2; ++qf)
            for (int ks = 0; ks < 2; ++ks)
                qfr[qf][ks] = *(const short8*)(Qb
                    + (size_t)(b * SEQ + qbase + qf * 16 + l15) * MODEL_DIM
                    + h * HDIM + ks * 32 + quad * 8);

        float m_i[2] = {-1e30f, -1e30f}, l_i[2] = {0.f, 0.f};
        f32x4 o_acc[4][2] = {};                    // [dt][qf]

        const int nkt = (q0 + 128) >> 6;
        uint4 kr0 = *(const uint4*)(kgp + (size_t)key0 * MODEL_DIM + c8);
        uint4 kr1 = *(const uint4*)(kgp + (size_t)(key0 + 32) * MODEL_DIM + c8);
        uint4 vr0 = *(const uint4*)(vgp + (size_t)key0 * (SEQ / 2) + c4);
        uint4 vr1 = *(const uint4*)(vgp + (size_t)(key0 + 32) * (SEQ / 2) + c4);

        for (int kt = 0; kt < nkt; ++kt) {
            const int k0 = kt * 64;
            u16* ksb = Ks[bufc];
            u16* vsb = Vs[bufc];
            *(uint4*)(&ksb[lko])        = kr0;
            *(uint4*)(&ksb[lko + 2048]) = kr1;
            *(uint4*)(&vsb[lko])        = vr0;
            *(uint4*)(&vsb[lko + 2048]) = vr1;
            __syncthreads();

            if (kt + 1 < nkt) {
                const int kn = k0 + 64;
                kr0 = *(const uint4*)(kgp + (size_t)(kn + key0) * MODEL_DIM + c8);
                kr1 = *(const uint4*)(kgp + (size_t)(kn + key0 + 32) * MODEL_DIM + c8);
                vr0 = *(const uint4*)(vgp + (size_t)key0 * (SEQ / 2) + (kn >> 1) + c4);
                vr1 = *(const uint4*)(vgp + (size_t)(key0 + 32) * (SEQ / 2)
                                      + (kn >> 1) + c4);
            }

            if (k0 <= qbase + 31) {
                f32x4 s[4][2] = {};
                for (int ks = 0; ks < 2; ++ks) {
                    short8 kfr[4];
                    for (int kf = 0; kf < 4; ++kf)
                        kfr[kf] = *(const short8*)(&ksb[(kf * 16 + l15) * 64
                                      + (((ks * 4 + quad) ^ (l15 & 7)) * 8)]);
                    __builtin_amdgcn_s_setprio(1);
                    for (int kf = 0; kf < 4; ++kf)
                        for (int qf = 0; qf < 2; ++qf)
                            s[kf][qf] = __builtin_amdgcn_mfma_f32_16x16x32_bf16(
                                            kfr[kf], qfr[qf][ks], s[kf][qf], 0, 0, 0);
                    __builtin_amdgcn_s_setprio(0);
                }
                for (int qf = 0; qf < 2; ++qf) {
                    int qg = qbase + qf * 16 + l15;
                    if (k0 + 63 > qbase + qf * 16) {
                        for (int kf = 0; kf < 4; ++kf)
                            for (int r = 0; r < 4; ++r)
                                if (k0 + kf * 16 + quad * 4 + r > qg)
                                    s[kf][qf][r] = -1e30f;
                    }
                    float t0 = fmaxf(fmaxf(s[0][qf][0], s[0][qf][1]),
                                     fmaxf(s[0][qf][2], s[0][qf][3]));
                    float t1 = fmaxf(fmaxf(s[1][qf][0], s[1][qf][1]),
                                     fmaxf(s[1][qf][2], s[1][qf][3]));
                    float t2 = fmaxf(fmaxf(s[2][qf][0], s[2][qf][1]),
                                     fmaxf(s[2][qf][2], s[2][qf][3]));
                    float t3 = fmaxf(fmaxf(s[3][qf][0], s[3][qf][1]),
                                     fmaxf(s[3][qf][2], s[3][qf][3]));
                    float rmax = fmaxf(fmaxf(t0, t1), fmaxf(t2, t3));
                    rmax = fmaxf(rmax, __shfl_xor(rmax, 16, 64));
                    rmax = fmaxf(rmax, __shfl_xor(rmax, 32, 64));
                    if (!__all(rmax <= m_i[qf] + 8.0f)) {
                        float mn = fmaxf(m_i[qf], rmax);
                        float alpha = exp2a(m_i[qf] - mn);
                        m_i[qf] = mn;
                        l_i[qf] *= alpha;
                        for (int dt = 0; dt < 4; ++dt)
                            for (int r = 0; r < 4; ++r) o_acc[dt][qf][r] *= alpha;
                    }
                    float mref = m_i[qf];
                    float psum = 0.f;
                    for (int kf = 0; kf < 4; ++kf)
                        for (int r = 0; r < 4; ++r) {
                            float p = exp2a(s[kf][qf][r] - mref);
                            s[kf][qf][r] = p;
                            psum += p;
                        }
                    psum += __shfl_xor(psum, 16, 64);
                    psum += __shfl_xor(psum, 32, 64);
                    l_i[qf] += psum;
                    for (int kf = 0; kf < 4; ++kf) {
                        uint2 w;
                        w.x = cvtpk(s[kf][qf][0], s[kf][qf][1]);
                        w.y = cvtpk(s[kf][qf][2], s[kf][qf][3]);
                        *(uint2*)(&pw[(qf * 16 + l15) * 72 + kf * 16 + quad * 4]) = w;
                    }
                }
                for (int ks = 0; ks < 2; ++ks) {
                    short8 pfr[2], vfr[4];
                    for (int qf = 0; qf < 2; ++qf)
                        pfr[qf] = *(const short8*)(&pw[(qf * 16 + l15) * 72
                                                       + ks * 32 + quad * 8]);
                    for (int dt = 0; dt < 4; ++dt)
                        vfr[dt] = *(const short8*)(&vsb[(dt * 16 + l15) * 64
                                      + (((ks * 4 + quad) ^ (l15 & 7)) * 8)]);
                    __builtin_amdgcn_s_setprio(1);
                    for (int dt = 0; dt < 4; ++dt)
                        for (int qf = 0; qf < 2; ++qf)
                            o_acc[dt][qf] = __builtin_amdgcn_mfma_f32_16x16x32_bf16(
                                                vfr[dt], pfr[qf], o_acc[dt][qf], 0, 0, 0);
                    __builtin_amdgcn_s_setprio(0);
                }
            }
            bufc ^= 1;
        }

        for (int qf = 0; qf < 2; ++qf) {
            float rl = 1.f / l_i[qf];
            int q = qbase + qf * 16 + l15;
            for (int dt = 0; dt < 4; ++dt) {
                uint2 w;
                w.x = cvtpk(o_acc[dt][qf][0] * rl, o_acc[dt][qf][1] * rl);
                w.y = cvtpk(o_acc[dt][qf][2] * rl, o_acc[dt][qf][3] * rl);
                *(uint2*)(&Ob[(size_t)(b * SEQ + q) * MODEL_DIM
                              + h * HDIM + dt * 16 + quad * 4]) = w;
            }
        }
    }
}

// --------------------------------------------------------------------- launcher
extern "C" void kernel_launch(void* const* d_in, const int* in_sizes, int n_in,
                              void* d_out, int out_size, void* d_ws, size_t ws_size,
                              hipStream_t stream) {
    const float* X  = (const float*)d_in[0];
    const float* Wq = (const float*)d_in[1];
    const float* bq = (const float*)d_in[2];
    const float* Wk = (const float*)d_in[3];
    const float* bk = (const float*)d_in[4];
    const float* Wv = (const float*)d_in[5];
    const float* bv = (const float*)d_in[6];
    const float* Wo = (const float*)d_in[7];
    const float* bo = (const float*)d_in[8];
    float* out = (float*)d_out;

    // ws: [Xb/Ob 16.78M][Wt 8.39M][Qb 16.78M][Kb 16.78M][unused][VT 16.78M]
    char* ws = (char*)d_ws;
    u16* Xb   = (u16*)ws;                       // aliased by Ob after QKV GEMM
    u16* Ob   = (u16*)ws;
    u16* Wt   = (u16*)(ws + 16777216);
    u16* Qb   = (u16*)(ws + 25165824);
    u16* Kb   = (u16*)(ws + 41943040);
    u32* VT32 = (u32*)(ws + 75497472);

    prep_k<<<dim3(12288), dim3(256), 0, stream>>>(X, Xb, Wq, Wk, Wv, Wo, Wt);
    gemm256qkv_k<<<dim3(32, 12), dim3(512), 0, stream>>>(Xb, Wt, Qb, Kb, VT32,
                                                         bq, bk, bv);
    attn_k<<<dim3(8, 16, 4), dim3(256), 0, stream>>>(Qb, Kb, VT32, Ob);
    gemm128o_k<<<dim3(64, 8), dim3(256), 0, stream>>>(Ob, Wt, out, bo);
}

// Round 12
// 258.260 us; speedup vs baseline: 1.3922x; 1.0231x over previous
//
#include <hip/hip_runtime.h>

typedef unsigned short u16;
typedef unsigned int   u32;
typedef __attribute__((ext_vector_type(4))) float f32x4;
typedef __attribute__((ext_vector_type(8))) short short8;

#define MODEL_DIM 1024
#define SEQ 2048
#define BATCH 4
#define NHEAD 16
#define HDIM 64
#define MTOT (BATCH*SEQ)                       /* 8192 */
#define ELEMS ((size_t)MTOT*MODEL_DIM)         /* 8388608 */

__device__ __forceinline__ u16 f2bf(float f) {
    u32 u = __float_as_uint(f);
    u = (u + 0x7fffu + ((u >> 16) & 1u)) >> 16;   // RNE
    return (u16)u;
}
__device__ __forceinline__ u32 pack2(float a, float b) {
    return (u32)f2bf(a) | ((u32)f2bf(b) << 16);
}
// packed RNE f32x2 -> bf16x2 (1 instr; no builtin on gfx950, T12 recipe)
__device__ __forceinline__ u32 cvtpk(float lo, float hi) {
    u32 r;
    asm("v_cvt_pk_bf16_f32 %0, %1, %2" : "=v"(r) : "v"(lo), "v"(hi));
    return r;
}
// raw 2^x (v_exp_f32); softmax runs in log2 domain (log2e folded into Q scale)
__device__ __forceinline__ float exp2a(float x) {
    float r;
    asm("v_exp_f32 %0, %1" : "=v"(r) : "v"(x));
    return r;
}

// async global->LDS 16B: wave-uniform LDS base + lane*16 (m97 pattern)
#define GLOAD16(g, l) __builtin_amdgcn_global_load_lds(                        \
        (const __attribute__((address_space(1))) unsigned int*)(g),            \
        (__attribute__((address_space(3))) unsigned int*)(l), 16, 0, 0)

// ------------------------- prep: cast X -> bf16  +  W[k][n] fp32 -> Wt[n][k] bf16
// flat grid: blocks [0, 8192) cast; blocks [8192, 12288) transpose W.
__global__ __launch_bounds__(256) void prep_k(const float* __restrict__ X,
                                              u16* __restrict__ Xb,
                                              const float* __restrict__ Wq,
                                              const float* __restrict__ Wk,
                                              const float* __restrict__ Wv,
                                              const float* __restrict__ Wo,
                                              u16* __restrict__ Wt) {
    const int bid = blockIdx.x, t = threadIdx.x;
    if (bid < 8192) {
        size_t i = ((size_t)bid * 256 + t) * 4;
        float4 v = *(const float4*)(X + i);
        uint2 o; o.x = pack2(v.x, v.y); o.y = pack2(v.z, v.w);
        *(uint2*)(Xb + i) = o;
        return;
    }
    __shared__ float tile[32][33];
    const int bid2 = bid - 8192;
    const int z = bid2 >> 10, rem = bid2 & 1023;
    const int by = rem >> 5, bx = rem & 31;
    const float* W = (z == 0) ? Wq : (z == 1) ? Wk : (z == 2) ? Wv : Wo;
    const int k0 = by * 32, n0 = bx * 32;
    const int x = t & 31, y = t >> 5;                   // 32 x 8
    for (int i = 0; i < 4; ++i)
        tile[y + i * 8][x] = W[(size_t)(k0 + y + i * 8) * MODEL_DIM + n0 + x];
    __syncthreads();
    u16* out = Wt + ((size_t)z << 20);
    for (int i = 0; i < 4; ++i)
        out[(size_t)(n0 + y + i * 8) * MODEL_DIM + k0 + x] = f2bf(tile[x][y + i * 8]);
}

// ------------------------------------------------ QKV GEMM 256x256, 8-phase
// T2+T3+T4+T5 template: 512 thr = 8 waves (2M x 4N), BK=64, double-buffered
// 128KB LDS, raw barriers, counted vmcnt, involutive XOR swizzle.
// All acc loops unrolled (rule #20). Verified R11.
__global__ __launch_bounds__(512, 2) void gemm256qkv_k(
        const u16* __restrict__ A, const u16* __restrict__ Wt,
        u16* __restrict__ Qb, u16* __restrict__ Kb, u32* __restrict__ VT,
        const float* __restrict__ bq, const float* __restrict__ bk,
        const float* __restrict__ bv) {
    __shared__ __align__(16) u16 Ls[65536];        // 128KB: 2 buf x (A 32K + B 32K)
    const int tid  = threadIdx.x;
    const int wv   = tid >> 6, lane = tid & 63;
    const int l15  = lane & 15, quad = lane >> 4;
    const int wr = wv >> 2, wc = wv & 3;           // wave = (M-half, N-quarter)
    const int bh = wc >> 1;                        // B-half this wave consumes
    const int sb = wr * 2 + (wc & 1);              // sibling idx among B stagers
    const int m0 = blockIdx.x * 256;
    const int region = blockIdx.y >> 2;            // 0=Q 1=K 2=V
    const int n0loc = (blockIdx.y & 3) * 256;

    const u16* Ag = A + (size_t)m0 * MODEL_DIM;
    const u16* Bg = Wt + ((size_t)region << 20) + (size_t)n0loc * MODEL_DIM;

    f32x4 acc[8][4] = {};

#define STAGE2(kt, d, q) do {                                                  \
    const int kk0_ = (kt) * 64;                                                \
    { int L_ = ((q) * 256 + wc * 64 + lane) * 16;                              \
      int P_ = L_ ^ (((L_ >> 7) & 7) << 4);                                    \
      GLOAD16(Ag + (size_t)(wr * 128 + (P_ >> 7)) * MODEL_DIM + kk0_           \
                 + ((P_ & 127) >> 1),                                          \
              &Ls[(d) * 32768 + wr * 8192 + (L_ >> 1)]); }                     \
    { int L_ = ((q) * 256 + sb * 64 + lane) * 16;                              \
      int P_ = L_ ^ (((L_ >> 7) & 7) << 4);                                    \
      GLOAD16(Bg + (size_t)(bh * 128 + (P_ >> 7)) * MODEL_DIM + kk0_           \
                 + ((P_ & 127) >> 1),                                          \
              &Ls[(d) * 32768 + 16384 + bh * 8192 + (L_ >> 1)]); }             \
} while (0)

#define LDA8(mf, ks) ({                                                        \
    int P_ = ((mf) * 16 + l15) * 128 + ((ks) * 4 + quad) * 16;                 \
    int L_ = P_ ^ (((P_ >> 7) & 7) << 4);                                      \
    *(const short8*)(ab + (L_ >> 1)); })
#define LDB8(nf, ks) ({                                                        \
    int P_ = ((wc & 1) * 64 + (nf) * 16 + l15) * 128 + ((ks) * 4 + quad) * 16; \
    int L_ = P_ ^ (((P_ >> 7) & 7) << 4);                                      \
    *(const short8*)(bb2 + (L_ >> 1)); })

#define PHASE_MFMA(MH)                                                         \
    __builtin_amdgcn_s_setprio(1);                                             \
    _Pragma("unroll")                                                          \
    for (int j2 = 0; j2 < 4; ++j2)                                             \
        _Pragma("unroll")                                                      \
        for (int nf2 = 0; nf2 < 4; ++nf2)                                      \
            acc[(MH) * 4 + j2][nf2] = __builtin_amdgcn_mfma_f32_16x16x32_bf16( \
                af[j2], bf[nf2], acc[(MH) * 4 + j2][nf2], 0, 0, 0);            \
    __builtin_amdgcn_s_setprio(0);

    STAGE2(0, 0, 0); STAGE2(0, 0, 1); STAGE2(0, 0, 2); STAGE2(0, 0, 3);

    for (int t = 0; t < 16; ++t) {
        const int pp2 = t & 1;
        const u16* ab  = &Ls[pp2 * 32768 + wr * 8192];
        const u16* bb2 = &Ls[pp2 * 32768 + 16384 + bh * 8192];
        const int dn = pp2 ^ 1;
        const bool more = (t + 1) < 16;
        short8 af[4], bf[4];
        if (more) STAGE2(t + 1, dn, 0);
        if (more) asm volatile("s_waitcnt vmcnt(2)" ::: "memory");
        else      asm volatile("s_waitcnt vmcnt(0)" ::: "memory");
        __builtin_amdgcn_s_barrier();
        __builtin_amdgcn_sched_barrier(0);
        #pragma unroll
        for (int nf = 0; nf < 4; ++nf) bf[nf] = LDB8(nf, 0);
        #pragma unroll
        for (int j = 0; j < 4; ++j) af[j] = LDA8(j, 0);
        PHASE_MFMA(0)
        __builtin_amdgcn_s_barrier();
        #pragma unroll
        for (int j = 0; j < 4; ++j) af[j] = LDA8(4 + j, 0);
        if (more) STAGE2(t + 1, dn, 1);
        __builtin_amdgcn_s_barrier();
        __builtin_amdgcn_sched_barrier(0);
        PHASE_MFMA(1)
        __builtin_amdgcn_s_barrier();
        #pragma unroll
        for (int nf = 0; nf < 4; ++nf) bf[nf] = LDB8(nf, 1);
        #pragma unroll
        for (int j = 0; j < 4; ++j) af[j] = LDA8(j, 1);
        if (more) STAGE2(t + 1, dn, 2);
        __builtin_amdgcn_s_barrier();
        __builtin_amdgcn_sched_barrier(0);
        PHASE_MFMA(0)
        __builtin_amdgcn_s_barrier();
        #pragma unroll
        for (int j = 0; j < 4; ++j) af[j] = LDA8(4 + j, 1);
        if (more) STAGE2(t + 1, dn, 3);
        __builtin_amdgcn_s_barrier();
        __builtin_amdgcn_sched_barrier(0);
        PHASE_MFMA(1)
        __builtin_amdgcn_s_barrier();
    }

    if (region < 2) {
        const float* bias = region ? bk : bq;
        u16* dst = region ? Kb : Qb;
        const float qsc = region ? 1.0f : 0.125f * 1.44269504f;
        const float cfr = -0.017989922f;               // -ln(10000)/512
        float invf[4];
        #pragma unroll
        for (int nf = 0; nf < 4; ++nf) {
            int c = n0loc + wc * 64 + nf * 16 + l15;
            invf[nf] = __expf((float)(c >> 1) * cfr);
        }
        const float sgn = (l15 & 1) ? 1.0f : -1.0f;    // even: x1*cs - x2*sn
        #pragma unroll
        for (int mf = 0; mf < 8; ++mf)
            #pragma unroll
            for (int r = 0; r < 4; ++r) {
                size_t rowg = (size_t)(m0 + wr * 128 + mf * 16 + quad * 4 + r);
                float fs = (float)(int)(rowg & 2047);
                #pragma unroll
                for (int nf = 0; nf < 4; ++nf) {
                    int c = n0loc + wc * 64 + nf * 16 + l15;
                    float v = acc[mf][nf][r] + bias[c];
                    float mate = __shfl_xor(v, 1, 64);
                    float sn, cs;
                    __sincosf(fs * invf[nf], &sn, &cs);
                    float o = (v * cs + sgn * mate * sn) * qsc;
                    dst[rowg * MODEL_DIM + c] = f2bf(o);
                }
            }
    } else {
        const int b_ = m0 >> 11;
        const int s0 = m0 & 2047;
        #pragma unroll
        for (int nf = 0; nf < 4; ++nf) {
            int c = n0loc + wc * 64 + nf * 16 + l15;
            float bvc = bv[c];
            u32* vtrow = VT + (size_t)((b_ * NHEAD + (c >> 6)) * HDIM
                                       + (c & 63)) * (SEQ / 2);
            #pragma unroll
            for (int mf = 0; mf < 8; ++mf) {
                int sb2 = s0 + wr * 128 + mf * 16 + quad * 4;
                uint2 w;
                w.x = cvtpk(acc[mf][nf][0] + bvc, acc[mf][nf][1] + bvc);
                w.y = cvtpk(acc[mf][nf][2] + bvc, acc[mf][nf][3] + bvc);
                *(uint2*)(vtrow + (sb2 >> 1)) = w;
            }
        }
    }
#undef STAGE2
#undef LDA8
#undef LDB8
#undef PHASE_MFMA
}

// ------------------------------------------------ O-proj GEMM 256x128, 8-phase
// Same template, BN=128: grid (32,8) = 256 blocks = 1/CU (256² would leave
// half the CUs idle at N=1024). 8 waves; wave owns 128x32 -> acc[8][2].
// LDS 96KB: A 32K x2buf + B 16K x2buf. 6 gloads/thread/tile (A x4 + B x2),
// distributed ph0:{A,B} ph1:{A,B} ph2:{A} ph3:{A}; boundary vmcnt(2).
__global__ __launch_bounds__(512) void gemm256o_k(
        const u16* __restrict__ A, const u16* __restrict__ Wt,
        float* __restrict__ outO, const float* __restrict__ bo) {
    __shared__ __align__(16) u16 Ls[49152];        // 96KB: 2 buf x (A 32K + B 16K)
    const int tid  = threadIdx.x;
    const int wv   = tid >> 6, lane = tid & 63;
    const int l15  = lane & 15, quad = lane >> 4;
    const int wr = wv >> 2, wc = wv & 3;           // wave = (M-half, N-quarter/32)
    const int m0 = blockIdx.x * 256;
    const int n0 = blockIdx.y * 128;

    const u16* Ag = A + (size_t)m0 * MODEL_DIM;
    const u16* Bg = Wt + ((size_t)3 << 20) + (size_t)n0 * MODEL_DIM;

    f32x4 acc[8][2] = {};

#define STAGE_A(kt, d, q) do {                                                 \
    const int kk0_ = (kt) * 64;                                                \
    int L_ = ((q) * 256 + wc * 64 + lane) * 16;                                \
    int P_ = L_ ^ (((L_ >> 7) & 7) << 4);                                      \
    GLOAD16(Ag + (size_t)(wr * 128 + (P_ >> 7)) * MODEL_DIM + kk0_             \
               + ((P_ & 127) >> 1),                                            \
            &Ls[(d) * 24576 + wr * 8192 + (L_ >> 1)]);                         \
} while (0)
#define STAGE_B(kt, d, q) do {                                                 \
    const int kk0_ = (kt) * 64;                                                \
    int L_ = ((q) * 512 + tid) * 16;                                           \
    int P_ = L_ ^ (((L_ >> 7) & 7) << 4);                                      \
    GLOAD16(Bg + (size_t)(P_ >> 7) * MODEL_DIM + kk0_ + ((P_ & 127) >> 1),     \
            &Ls[(d) * 24576 + 16384 + (L_ >> 1)]);                             \
} while (0)

#define LDA8O(mf, ks) ({                                                       \
    int P_ = ((mf) * 16 + l15) * 128 + ((ks) * 4 + quad) * 16;                 \
    int L_ = P_ ^ (((P_ >> 7) & 7) << 4);                                      \
    *(const short8*)(ab + (L_ >> 1)); })
#define LDB8O(nf, ks) ({                                                       \
    int P_ = (wc * 32 + (nf) * 16 + l15) * 128 + ((ks) * 4 + quad) * 16;       \
    int L_ = P_ ^ (((P_ >> 7) & 7) << 4);                                      \
    *(const short8*)(bbO + (L_ >> 1)); })

#define PHASE_MFMA_O(MH)                                                       \
    __builtin_amdgcn_s_setprio(1);                                             \
    _Pragma("unroll")                                                          \
    for (int j2 = 0; j2 < 4; ++j2)                                             \
        _Pragma("unroll")                                                      \
        for (int nf2 = 0; nf2 < 2; ++nf2)                                      \
            acc[(MH) * 4 + j2][nf2] = __builtin_amdgcn_mfma_f32_16x16x32_bf16( \
                af[j2], bf[nf2], acc[(MH) * 4 + j2][nf2], 0, 0, 0);            \
    __builtin_amdgcn_s_setprio(0);

    // prologue: tile 0 into buf 0 (6 gloads/thread, order A0,B0,A1,B1,A2,A3)
    STAGE_A(0, 0, 0); STAGE_B(0, 0, 0);
    STAGE_A(0, 0, 1); STAGE_B(0, 0, 1);
    STAGE_A(0, 0, 2); STAGE_A(0, 0, 3);

    for (int t = 0; t < 16; ++t) {
        const int pp2 = t & 1;
        const u16* ab  = &Ls[pp2 * 24576 + wr * 8192];
        const u16* bbO = &Ls[pp2 * 24576 + 16384];
        const int dn = pp2 ^ 1;
        const bool more = (t + 1) < 16;
        short8 af[4], bf[2];
        // ---- phase 0 (ks=0, mh=0): boundary — counted vmcnt, then publish
        if (more) { STAGE_A(t + 1, dn, 0); STAGE_B(t + 1, dn, 0); }
        if (more) asm volatile("s_waitcnt vmcnt(2)" ::: "memory");
        else      asm volatile("s_waitcnt vmcnt(0)" ::: "memory");
        __builtin_amdgcn_s_barrier();
        __builtin_amdgcn_sched_barrier(0);
        #pragma unroll
        for (int nf = 0; nf < 2; ++nf) bf[nf] = LDB8O(nf, 0);
        #pragma unroll
        for (int j = 0; j < 4; ++j) af[j] = LDA8O(j, 0);
        PHASE_MFMA_O(0)
        __builtin_amdgcn_s_barrier();
        // ---- phase 1 (ks=0, mh=1)
        #pragma unroll
        for (int j = 0; j < 4; ++j) af[j] = LDA8O(4 + j, 0);
        if (more) { STAGE_A(t + 1, dn, 1); STAGE_B(t + 1, dn, 1); }
        __builtin_amdgcn_s_barrier();
        __builtin_amdgcn_sched_barrier(0);
        PHASE_MFMA_O(1)
        __builtin_amdgcn_s_barrier();
        // ---- phase 2 (ks=1, mh=0)
        #pragma unroll
        for (int nf = 0; nf < 2; ++nf) bf[nf] = LDB8O(nf, 1);
        #pragma unroll
        for (int j = 0; j < 4; ++j) af[j] = LDA8O(j, 1);
        if (more) STAGE_A(t + 1, dn, 2);
        __builtin_amdgcn_s_barrier();
        __builtin_amdgcn_sched_barrier(0);
        PHASE_MFMA_O(0)
        __builtin_amdgcn_s_barrier();
        // ---- phase 3 (ks=1, mh=1)
        #pragma unroll
        for (int j = 0; j < 4; ++j) af[j] = LDA8O(4 + j, 1);
        if (more) STAGE_A(t + 1, dn, 3);
        __builtin_amdgcn_s_barrier();
        __builtin_amdgcn_sched_barrier(0);
        PHASE_MFMA_O(1)
        __builtin_amdgcn_s_barrier();
    }

    // epilogue: fp32 out + bo, fully unrolled (rule #20)
    #pragma unroll
    for (int mf = 0; mf < 8; ++mf)
        #pragma unroll
        for (int r = 0; r < 4; ++r) {
            size_t rowg = (size_t)(m0 + wr * 128 + mf * 16 + quad * 4 + r);
            #pragma unroll
            for (int nf = 0; nf < 2; ++nf) {
                int colg = n0 + wc * 32 + nf * 16 + l15;
                outO[rowg * MODEL_DIM + colg] = acc[mf][nf][r] + bo[colg];
            }
        }
#undef STAGE_A
#undef STAGE_B
#undef LDA8O
#undef LDB8O
#undef PHASE_MFMA_O
}

// ------------------------------------------------------- flash attention (causal)
// grid (8,16,4); 256 thr = 4 waves; wave owns 32 q-rows of the active q-tile.
// Causal pair-balancing; T14 dbuf pipeline; T13 defer-max; T5 setprio; exp2.
__global__ __launch_bounds__(256, 2) void attn_k(const u16* __restrict__ Qb,
                                                 const u16* __restrict__ Kb,
                                                 const u32* __restrict__ VT32,
                                                 u16* __restrict__ Ob) {
    __shared__ __align__(16) u16 Ks[2][64 * 64];   // [key][dim], chunk-XOR swizzle
    __shared__ __align__(16) u16 Vs[2][64 * 64];   // [d][key],   chunk-XOR swizzle
    __shared__ __align__(16) u16 Pl[4 * 32 * 72];  // per-wave P^T [q][key], pad 8
    const int tid  = threadIdx.x;
    const int wave = tid >> 6, lane = tid & 63;
    const int l15  = lane & 15, quad = lane >> 4;
    const int j = blockIdx.x;                      // 0..7 pair index
    const int h = blockIdx.y, b = blockIdx.z;
    u16* pw = &Pl[wave * 32 * 72];

    const int key0 = tid >> 3;                     // 0..31
    const int c8   = (tid & 7) * 8;                // u16 units
    const int c4   = (tid & 7) * 4;                // u32 units (VT rows)
    const int lko  = key0 * 64 + (((tid & 7) ^ (key0 & 7)) * 8);   // LDS dst
    const u16* kgp = Kb + (size_t)(b * SEQ) * MODEL_DIM + h * HDIM;
    const u32* vgp = VT32 + (size_t)((b * NHEAD + h) * HDIM) * (SEQ / 2);

    int bufc = 0;                                  // buffer parity, spans passes
    for (int pp = 0; pp < 2; ++pp) {
        const int qt = pp ? j : 15 - j;            // heavy tile first
        const int q0 = qt * 128;
        const int qbase = q0 + wave * 32;

        short8 qfr[2][2];
        for (int qf = 0; qf < 2; ++qf)
            for (int ks = 0; ks < 2; ++ks)
                qfr[qf][ks] = *(const short8*)(Qb
                    + (size_t)(b * SEQ + qbase + qf * 16 + l15) * MODEL_DIM
                    + h * HDIM + ks * 32 + quad * 8);

        float m_i[2] = {-1e30f, -1e30f}, l_i[2] = {0.f, 0.f};
        f32x4 o_acc[4][2] = {};                    // [dt][qf]

        const int nkt = (q0 + 128) >> 6;
        uint4 kr0 = *(const uint4*)(kgp + (size_t)key0 * MODEL_DIM + c8);
        uint4 kr1 = *(const uint4*)(kgp + (size_t)(key0 + 32) * MODEL_DIM + c8);
        uint4 vr0 = *(const uint4*)(vgp + (size_t)key0 * (SEQ / 2) + c4);
        uint4 vr1 = *(const uint4*)(vgp + (size_t)(key0 + 32) * (SEQ / 2) + c4);

        for (int kt = 0; kt < nkt; ++kt) {
            const int k0 = kt * 64;
            u16* ksb = Ks[bufc];
            u16* vsb = Vs[bufc];
            *(uint4*)(&ksb[lko])        = kr0;
            *(uint4*)(&ksb[lko + 2048]) = kr1;
            *(uint4*)(&vsb[lko])        = vr0;
            *(uint4*)(&vsb[lko + 2048]) = vr1;
            __syncthreads();

            if (kt + 1 < nkt) {
                const int kn = k0 + 64;
                kr0 = *(const uint4*)(kgp + (size_t)(kn + key0) * MODEL_DIM + c8);
                kr1 = *(const uint4*)(kgp + (size_t)(kn + key0 + 32) * MODEL_DIM + c8);
                vr0 = *(const uint4*)(vgp + (size_t)key0 * (SEQ / 2) + (kn >> 1) + c4);
                vr1 = *(const uint4*)(vgp + (size_t)(key0 + 32) * (SEQ / 2)
                                      + (kn >> 1) + c4);
            }

            if (k0 <= qbase + 31) {
                f32x4 s[4][2] = {};
                for (int ks = 0; ks < 2; ++ks) {
                    short8 kfr[4];
                    for (int kf = 0; kf < 4; ++kf)
                        kfr[kf] = *(const short8*)(&ksb[(kf * 16 + l15) * 64
                                      + (((ks * 4 + quad) ^ (l15 & 7)) * 8)]);
                    __builtin_amdgcn_s_setprio(1);
                    for (int kf = 0; kf < 4; ++kf)
                        for (int qf = 0; qf < 2; ++qf)
                            s[kf][qf] = __builtin_amdgcn_mfma_f32_16x16x32_bf16(
                                            kfr[kf], qfr[qf][ks], s[kf][qf], 0, 0, 0);
                    __builtin_amdgcn_s_setprio(0);
                }
                for (int qf = 0; qf < 2; ++qf) {
                    int qg = qbase + qf * 16 + l15;
                    if (k0 + 63 > qbase + qf * 16) {
                        for (int kf = 0; kf < 4; ++kf)
                            for (int r = 0; r < 4; ++r)
                                if (k0 + kf * 16 + quad * 4 + r > qg)
                                    s[kf][qf][r] = -1e30f;
                    }
                    float t0 = fmaxf(fmaxf(s[0][qf][0], s[0][qf][1]),
                                     fmaxf(s[0][qf][2], s[0][qf][3]));
                    float t1 = fmaxf(fmaxf(s[1][qf][0], s[1][qf][1]),
                                     fmaxf(s[1][qf][2], s[1][qf][3]));
                    float t2 = fmaxf(fmaxf(s[2][qf][0], s[2][qf][1]),
                                     fmaxf(s[2][qf][2], s[2][qf][3]));
                    float t3 = fmaxf(fmaxf(s[3][qf][0], s[3][qf][1]),
                                     fmaxf(s[3][qf][2], s[3][qf][3]));
                    float rmax = fmaxf(fmaxf(t0, t1), fmaxf(t2, t3));
                    rmax = fmaxf(rmax, __shfl_xor(rmax, 16, 64));
                    rmax = fmaxf(rmax, __shfl_xor(rmax, 32, 64));
                    if (!__all(rmax <= m_i[qf] + 8.0f)) {
                        float mn = fmaxf(m_i[qf], rmax);
                        float alpha = exp2a(m_i[qf] - mn);
                        m_i[qf] = mn;
                        l_i[qf] *= alpha;
                        for (int dt = 0; dt < 4; ++dt)
                            for (int r = 0; r < 4; ++r) o_acc[dt][qf][r] *= alpha;
                    }
                    float mref = m_i[qf];
                    float psum = 0.f;
                    for (int kf = 0; kf < 4; ++kf)
                        for (int r = 0; r < 4; ++r) {
                            float p = exp2a(s[kf][qf][r] - mref);
                            s[kf][qf][r] = p;
                            psum += p;
                        }
                    psum += __shfl_xor(psum, 16, 64);
                    psum += __shfl_xor(psum, 32, 64);
                    l_i[qf] += psum;
                    for (int kf = 0; kf < 4; ++kf) {
                        uint2 w;
                        w.x = cvtpk(s[kf][qf][0], s[kf][qf][1]);
                        w.y = cvtpk(s[kf][qf][2], s[kf][qf][3]);
                        *(uint2*)(&pw[(qf * 16 + l15) * 72 + kf * 16 + quad * 4]) = w;
                    }
                }
                for (int ks = 0; ks < 2; ++ks) {
                    short8 pfr[2], vfr[4];
                    for (int qf = 0; qf < 2; ++qf)
                        pfr[qf] = *(const short8*)(&pw[(qf * 16 + l15) * 72
                                                       + ks * 32 + quad * 8]);
                    for (int dt = 0; dt < 4; ++dt)
                        vfr[dt] = *(const short8*)(&vsb[(dt * 16 + l15) * 64
                                      + (((ks * 4 + quad) ^ (l15 & 7)) * 8)]);
                    __builtin_amdgcn_s_setprio(1);
                    for (int dt = 0; dt < 4; ++dt)
                        for (int qf = 0; qf < 2; ++qf)
                            o_acc[dt][qf] = __builtin_amdgcn_mfma_f32_16x16x32_bf16(
                                                vfr[dt], pfr[qf], o_acc[dt][qf], 0, 0, 0);
                    __builtin_amdgcn_s_setprio(0);
                }
            }
            bufc ^= 1;
        }

        for (int qf = 0; qf < 2; ++qf) {
            float rl = 1.f / l_i[qf];
            int q = qbase + qf * 16 + l15;
            for (int dt = 0; dt < 4; ++dt) {
                uint2 w;
                w.x = cvtpk(o_acc[dt][qf][0] * rl, o_acc[dt][qf][1] * rl);
                w.y = cvtpk(o_acc[dt][qf][2] * rl, o_acc[dt][qf][3] * rl);
                *(uint2*)(&Ob[(size_t)(b * SEQ + q) * MODEL_DIM
                              + h * HDIM + dt * 16 + quad * 4]) = w;
            }
        }
    }
}

// --------------------------------------------------------------------- launcher
extern "C" void kernel_launch(void* const* d_in, const int* in_sizes, int n_in,
                              void* d_out, int out_size, void* d_ws, size_t ws_size,
                              hipStream_t stream) {
    const float* X  = (const float*)d_in[0];
    const float* Wq = (const float*)d_in[1];
    const float* bq = (const float*)d_in[2];
    const float* Wk = (const float*)d_in[3];
    const float* bk = (const float*)d_in[4];
    const float* Wv = (const float*)d_in[5];
    const float* bv = (const float*)d_in[6];
    const float* Wo = (const float*)d_in[7];
    const float* bo = (const float*)d_in[8];
    float* out = (float*)d_out;

    // ws: [Xb/Ob 16.78M][Wt 8.39M][Qb 16.78M][Kb 16.78M][unused][VT 16.78M]
    char* ws = (char*)d_ws;
    u16* Xb   = (u16*)ws;                       // aliased by Ob after QKV GEMM
    u16* Ob   = (u16*)ws;
    u16* Wt   = (u16*)(ws + 16777216);
    u16* Qb   = (u16*)(ws + 25165824);
    u16* Kb   = (u16*)(ws + 41943040);
    u32* VT32 = (u32*)(ws + 75497472);

    prep_k<<<dim3(12288), dim3(256), 0, stream>>>(X, Xb, Wq, Wk, Wv, Wo, Wt);
    gemm256qkv_k<<<dim3(32, 12), dim3(512), 0, stream>>>(Xb, Wt, Qb, Kb, VT32,
                                                         bq, bk, bv);
    attn_k<<<dim3(8, 16, 4), dim3(256), 0, stream>>>(Qb, Kb, VT32, Ob);
    gemm256o_k<<<dim3(32, 8), dim3(512), 0, stream>>>(Ob, Wt, out, bo);
}

// Round 14
// 256.196 us; speedup vs baseline: 1.4034x; 1.0081x over previous
//
#include <hip/hip_runtime.h>

typedef unsigned short u16;
typedef unsigned int   u32;
typedef __attribute__((ext_vector_type(4))) float f32x4;
typedef __attribute__((ext_vector_type(8))) short short8;

#define MODEL_DIM 1024
#define SEQ 2048
#define BATCH 4
#define NHEAD 16
#define HDIM 64
#define MTOT (BATCH*SEQ)                       /* 8192 */
#define ELEMS ((size_t)MTOT*MODEL_DIM)         /* 8388608 */

__device__ __forceinline__ u16 f2bf(float f) {
    u32 u = __float_as_uint(f);
    u = (u + 0x7fffu + ((u >> 16) & 1u)) >> 16;   // RNE
    return (u16)u;
}
__device__ __forceinline__ u32 pack2(float a, float b) {
    return (u32)f2bf(a) | ((u32)f2bf(b) << 16);
}
// packed RNE f32x2 -> bf16x2 (1 instr; no builtin on gfx950, T12 recipe)
__device__ __forceinline__ u32 cvtpk(float lo, float hi) {
    u32 r;
    asm("v_cvt_pk_bf16_f32 %0, %1, %2" : "=v"(r) : "v"(lo), "v"(hi));
    return r;
}
// raw 2^x (v_exp_f32); softmax runs in log2 domain (log2e folded into Q scale)
__device__ __forceinline__ float exp2a(float x) {
    float r;
    asm("v_exp_f32 %0, %1" : "=v"(r) : "v"(x));
    return r;
}

// async global->LDS 16B: wave-uniform LDS base + lane*16 (m97 pattern)
#define GLOAD16(g, l) __builtin_amdgcn_global_load_lds(                        \
        (const __attribute__((address_space(1))) unsigned int*)(g),            \
        (__attribute__((address_space(3))) unsigned int*)(l), 16, 0, 0)

// ------------------------- prep: cast X -> bf16  +  W[k][n] fp32 -> Wt[n][k] bf16
// flat grid: blocks [0, 8192) cast; blocks [8192, 12288) transpose W.
__global__ __launch_bounds__(256) void prep_k(const float* __restrict__ X,
                                              u16* __restrict__ Xb,
                                              const float* __restrict__ Wq,
                                              const float* __restrict__ Wk,
                                              const float* __restrict__ Wv,
                                              const float* __restrict__ Wo,
                                              u16* __restrict__ Wt) {
    const int bid = blockIdx.x, t = threadIdx.x;
    if (bid < 8192) {
        size_t i = ((size_t)bid * 256 + t) * 4;
        float4 v = *(const float4*)(X + i);
        uint2 o; o.x = pack2(v.x, v.y); o.y = pack2(v.z, v.w);
        *(uint2*)(Xb + i) = o;
        return;
    }
    __shared__ float tile[32][33];
    const int bid2 = bid - 8192;
    const int z = bid2 >> 10, rem = bid2 & 1023;
    const int by = rem >> 5, bx = rem & 31;
    const float* W = (z == 0) ? Wq : (z == 1) ? Wk : (z == 2) ? Wv : Wo;
    const int k0 = by * 32, n0 = bx * 32;
    const int x = t & 31, y = t >> 5;                   // 32 x 8
    for (int i = 0; i < 4; ++i)
        tile[y + i * 8][x] = W[(size_t)(k0 + y + i * 8) * MODEL_DIM + n0 + x];
    __syncthreads();
    u16* out = Wt + ((size_t)z << 20);
    for (int i = 0; i < 4; ++i)
        out[(size_t)(n0 + y + i * 8) * MODEL_DIM + k0 + x] = f2bf(tile[x][y + i * 8]);
}

// ------------------------------------------ QKV GEMM 256x128, 8-phase template
// R13: re-tiled from 256x256 (grid 384 = 1.5 blocks/CU -> 25% tail loss) to
// 256x128 (grid (32,24) = 768 = 3.0 rounds/CU, every round full). Body is the
// R12-verified gemm256o_k structure (same STAGE/vmcnt invariant: per-wave
// drain vmcnt(2) + barrier join); epilogues are the R11-verified RoPE/VT-pack
// cut to nf<2. acc[8][2] (64 regs). LDS 96KB.
__global__ __launch_bounds__(512) void gemm256qkv_k(
        const u16* __restrict__ A, const u16* __restrict__ Wt,
        u16* __restrict__ Qb, u16* __restrict__ Kb, u32* __restrict__ VT,
        const float* __restrict__ bq, const float* __restrict__ bk,
        const float* __restrict__ bv) {
    __shared__ __align__(16) u16 Ls[49152];        // 96KB: 2 buf x (A 32K + B 16K)
    const int tid  = threadIdx.x;
    const int wv   = tid >> 6, lane = tid & 63;
    const int l15  = lane & 15, quad = lane >> 4;
    const int wr = wv >> 2, wc = wv & 3;           // wave = (M-half, N-quarter/32)
    const int m0 = blockIdx.x * 256;
    const int region = blockIdx.y >> 3;            // 0=Q 1=K 2=V
    const int n0 = (blockIdx.y & 7) * 128;

    const u16* Ag = A + (size_t)m0 * MODEL_DIM;
    const u16* Bg = Wt + ((size_t)region << 20) + (size_t)n0 * MODEL_DIM;

    f32x4 acc[8][2] = {};

#define STAGE_A(kt, d, q) do {                                                 \
    const int kk0_ = (kt) * 64;                                                \
    int L_ = ((q) * 256 + wc * 64 + lane) * 16;                                \
    int P_ = L_ ^ (((L_ >> 7) & 7) << 4);                                      \
    GLOAD16(Ag + (size_t)(wr * 128 + (P_ >> 7)) * MODEL_DIM + kk0_             \
               + ((P_ & 127) >> 1),                                            \
            &Ls[(d) * 24576 + wr * 8192 + (L_ >> 1)]);                         \
} while (0)
#define STAGE_B(kt, d, q) do {                                                 \
    const int kk0_ = (kt) * 64;                                                \
    int L_ = ((q) * 512 + tid) * 16;                                           \
    int P_ = L_ ^ (((L_ >> 7) & 7) << 4);                                      \
    GLOAD16(Bg + (size_t)(P_ >> 7) * MODEL_DIM + kk0_ + ((P_ & 127) >> 1),     \
            &Ls[(d) * 24576 + 16384 + (L_ >> 1)]);                             \
} while (0)

#define LDA8Q(mf, ks) ({                                                       \
    int P_ = ((mf) * 16 + l15) * 128 + ((ks) * 4 + quad) * 16;                 \
    int L_ = P_ ^ (((P_ >> 7) & 7) << 4);                                      \
    *(const short8*)(ab + (L_ >> 1)); })
#define LDB8Q(nf, ks) ({                                                       \
    int P_ = (wc * 32 + (nf) * 16 + l15) * 128 + ((ks) * 4 + quad) * 16;       \
    int L_ = P_ ^ (((P_ >> 7) & 7) << 4);                                      \
    *(const short8*)(bbQ + (L_ >> 1)); })

#define PHASE_MFMA_Q(MH)                                                       \
    __builtin_amdgcn_s_setprio(1);                                             \
    _Pragma("unroll")                                                          \
    for (int j2 = 0; j2 < 4; ++j2)                                             \
        _Pragma("unroll")                                                      \
        for (int nf2 = 0; nf2 < 2; ++nf2)                                      \
            acc[(MH) * 4 + j2][nf2] = __builtin_amdgcn_mfma_f32_16x16x32_bf16( \
                af[j2], bf[nf2], acc[(MH) * 4 + j2][nf2], 0, 0, 0);            \
    __builtin_amdgcn_s_setprio(0);

    // prologue: tile 0 into buf 0 (6 gloads/thread)
    STAGE_A(0, 0, 0); STAGE_B(0, 0, 0);
    STAGE_A(0, 0, 1); STAGE_B(0, 0, 1);
    STAGE_A(0, 0, 2); STAGE_A(0, 0, 3);

    for (int t = 0; t < 16; ++t) {
        const int pp2 = t & 1;
        const u16* ab  = &Ls[pp2 * 24576 + wr * 8192];
        const u16* bbQ = &Ls[pp2 * 24576 + 16384];
        const int dn = pp2 ^ 1;
        const bool more = (t + 1) < 16;
        short8 af[4], bf[2];
        // ---- phase 0 (ks=0, mh=0): boundary — counted vmcnt, then publish
        if (more) { STAGE_A(t + 1, dn, 0); STAGE_B(t + 1, dn, 0); }
        if (more) asm volatile("s_waitcnt vmcnt(2)" ::: "memory");
        else      asm volatile("s_waitcnt vmcnt(0)" ::: "memory");
        __builtin_amdgcn_s_barrier();
        __builtin_amdgcn_sched_barrier(0);
        #pragma unroll
        for (int nf = 0; nf < 2; ++nf) bf[nf] = LDB8Q(nf, 0);
        #pragma unroll
        for (int j = 0; j < 4; ++j) af[j] = LDA8Q(j, 0);
        PHASE_MFMA_Q(0)
        __builtin_amdgcn_s_barrier();
        // ---- phase 1 (ks=0, mh=1)
        #pragma unroll
        for (int j = 0; j < 4; ++j) af[j] = LDA8Q(4 + j, 0);
        if (more) { STAGE_A(t + 1, dn, 1); STAGE_B(t + 1, dn, 1); }
        __builtin_amdgcn_s_barrier();
        __builtin_amdgcn_sched_barrier(0);
        PHASE_MFMA_Q(1)
        __builtin_amdgcn_s_barrier();
        // ---- phase 2 (ks=1, mh=0)
        #pragma unroll
        for (int nf = 0; nf < 2; ++nf) bf[nf] = LDB8Q(nf, 1);
        #pragma unroll
        for (int j = 0; j < 4; ++j) af[j] = LDA8Q(j, 1);
        if (more) STAGE_A(t + 1, dn, 2);
        __builtin_amdgcn_s_barrier();
        __builtin_amdgcn_sched_barrier(0);
        PHASE_MFMA_Q(0)
        __builtin_amdgcn_s_barrier();
        // ---- phase 3 (ks=1, mh=1)
        #pragma unroll
        for (int j = 0; j < 4; ++j) af[j] = LDA8Q(4 + j, 1);
        if (more) STAGE_A(t + 1, dn, 3);
        __builtin_amdgcn_s_barrier();
        __builtin_amdgcn_sched_barrier(0);
        PHASE_MFMA_Q(1)
        __builtin_amdgcn_s_barrier();
    }

    // ------------- epilogue (all acc loops unrolled — rule #20)
    if (region < 2) {
        const float* bias = region ? bk : bq;
        u16* dst = region ? Kb : Qb;
        const float qsc = region ? 1.0f : 0.125f * 1.44269504f;
        const float cfr = -0.017989922f;               // -ln(10000)/512
        float invf[2];
        #pragma unroll
        for (int nf = 0; nf < 2; ++nf) {
            int c = n0 + wc * 32 + nf * 16 + l15;
            invf[nf] = __expf((float)(c >> 1) * cfr);
        }
        const float sgn = (l15 & 1) ? 1.0f : -1.0f;    // even: x1*cs - x2*sn
        #pragma unroll
        for (int mf = 0; mf < 8; ++mf)
            #pragma unroll
            for (int r = 0; r < 4; ++r) {
                size_t rowg = (size_t)(m0 + wr * 128 + mf * 16 + quad * 4 + r);
                float fs = (float)(int)(rowg & 2047);
                #pragma unroll
                for (int nf = 0; nf < 2; ++nf) {
                    int c = n0 + wc * 32 + nf * 16 + l15;
                    float v = acc[mf][nf][r] + bias[c];
                    float mate = __shfl_xor(v, 1, 64);
                    float sn, cs;
                    __sincosf(fs * invf[nf], &sn, &cs);
                    float o = (v * cs + sgn * mate * sn) * qsc;
                    dst[rowg * MODEL_DIM + c] = f2bf(o);
                }
            }
    } else {
        // V: pack + store V^T (VT32) directly from acc (R9-proven pattern)
        const int b_ = m0 >> 11;
        const int s0 = m0 & 2047;
        #pragma unroll
        for (int nf = 0; nf < 2; ++nf) {
            int c = n0 + wc * 32 + nf * 16 + l15;
            float bvc = bv[c];
            u32* vtrow = VT + (size_t)((b_ * NHEAD + (c >> 6)) * HDIM
                                       + (c & 63)) * (SEQ / 2);
            #pragma unroll
            for (int mf = 0; mf < 8; ++mf) {
                int sb2 = s0 + wr * 128 + mf * 16 + quad * 4;
                uint2 w;
                w.x = cvtpk(acc[mf][nf][0] + bvc, acc[mf][nf][1] + bvc);
                w.y = cvtpk(acc[mf][nf][2] + bvc, acc[mf][nf][3] + bvc);
                *(uint2*)(vtrow + (sb2 >> 1)) = w;
            }
        }
    }
#undef STAGE_A
#undef STAGE_B
#undef LDA8Q
#undef LDB8Q
#undef PHASE_MFMA_Q
}

// ------------------------------------------------ O-proj GEMM 256x128, 8-phase
// Verified R12. grid (32,8) = 256 blocks = 1/CU. acc[8][2]; LDS 96KB.
__global__ __launch_bounds__(512) void gemm256o_k(
        const u16* __restrict__ A, const u16* __restrict__ Wt,
        float* __restrict__ outO, const float* __restrict__ bo) {
    __shared__ __align__(16) u16 Ls[49152];        // 96KB: 2 buf x (A 32K + B 16K)
    const int tid  = threadIdx.x;
    const int wv   = tid >> 6, lane = tid & 63;
    const int l15  = lane & 15, quad = lane >> 4;
    const int wr = wv >> 2, wc = wv & 3;           // wave = (M-half, N-quarter/32)
    const int m0 = blockIdx.x * 256;
    const int n0 = blockIdx.y * 128;

    const u16* Ag = A + (size_t)m0 * MODEL_DIM;
    const u16* Bg = Wt + ((size_t)3 << 20) + (size_t)n0 * MODEL_DIM;

    f32x4 acc[8][2] = {};

#define STAGE_A(kt, d, q) do {                                                 \
    const int kk0_ = (kt) * 64;                                                \
    int L_ = ((q) * 256 + wc * 64 + lane) * 16;                                \
    int P_ = L_ ^ (((L_ >> 7) & 7) << 4);                                      \
    GLOAD16(Ag + (size_t)(wr * 128 + (P_ >> 7)) * MODEL_DIM + kk0_             \
               + ((P_ & 127) >> 1),                                            \
            &Ls[(d) * 24576 + wr * 8192 + (L_ >> 1)]);                         \
} while (0)
#define STAGE_B(kt, d, q) do {                                                 \
    const int kk0_ = (kt) * 64;                                                \
    int L_ = ((q) * 512 + tid) * 16;                                           \
    int P_ = L_ ^ (((L_ >> 7) & 7) << 4);                                      \
    GLOAD16(Bg + (size_t)(P_ >> 7) * MODEL_DIM + kk0_ + ((P_ & 127) >> 1),     \
            &Ls[(d) * 24576 + 16384 + (L_ >> 1)]);                             \
} while (0)

#define LDA8O(mf, ks) ({                                                       \
    int P_ = ((mf) * 16 + l15) * 128 + ((ks) * 4 + quad) * 16;                 \
    int L_ = P_ ^ (((P_ >> 7) & 7) << 4);                                      \
    *(const short8*)(ab + (L_ >> 1)); })
#define LDB8O(nf, ks) ({                                                       \
    int P_ = (wc * 32 + (nf) * 16 + l15) * 128 + ((ks) * 4 + quad) * 16;       \
    int L_ = P_ ^ (((P_ >> 7) & 7) << 4);                                      \
    *(const short8*)(bbO + (L_ >> 1)); })

#define PHASE_MFMA_O(MH)                                                       \
    __builtin_amdgcn_s_setprio(1);                                             \
    _Pragma("unroll")                                                          \
    for (int j2 = 0; j2 < 4; ++j2)                                             \
        _Pragma("unroll")                                                      \
        for (int nf2 = 0; nf2 < 2; ++nf2)                                      \
            acc[(MH) * 4 + j2][nf2] = __builtin_amdgcn_mfma_f32_16x16x32_bf16( \
                af[j2], bf[nf2], acc[(MH) * 4 + j2][nf2], 0, 0, 0);            \
    __builtin_amdgcn_s_setprio(0);

    STAGE_A(0, 0, 0); STAGE_B(0, 0, 0);
    STAGE_A(0, 0, 1); STAGE_B(0, 0, 1);
    STAGE_A(0, 0, 2); STAGE_A(0, 0, 3);

    for (int t = 0; t < 16; ++t) {
        const int pp2 = t & 1;
        const u16* ab  = &Ls[pp2 * 24576 + wr * 8192];
        const u16* bbO = &Ls[pp2 * 24576 + 16384];
        const int dn = pp2 ^ 1;
        const bool more = (t + 1) < 16;
        short8 af[4], bf[2];
        if (more) { STAGE_A(t + 1, dn, 0); STAGE_B(t + 1, dn, 0); }
        if (more) asm volatile("s_waitcnt vmcnt(2)" ::: "memory");
        else      asm volatile("s_waitcnt vmcnt(0)" ::: "memory");
        __builtin_amdgcn_s_barrier();
        __builtin_amdgcn_sched_barrier(0);
        #pragma unroll
        for (int nf = 0; nf < 2; ++nf) bf[nf] = LDB8O(nf, 0);
        #pragma unroll
        for (int j = 0; j < 4; ++j) af[j] = LDA8O(j, 0);
        PHASE_MFMA_O(0)
        __builtin_amdgcn_s_barrier();
        #pragma unroll
        for (int j = 0; j < 4; ++j) af[j] = LDA8O(4 + j, 0);
        if (more) { STAGE_A(t + 1, dn, 1); STAGE_B(t + 1, dn, 1); }
        __builtin_amdgcn_s_barrier();
        __builtin_amdgcn_sched_barrier(0);
        PHASE_MFMA_O(1)
        __builtin_amdgcn_s_barrier();
        #pragma unroll
        for (int nf = 0; nf < 2; ++nf) bf[nf] = LDB8O(nf, 1);
        #pragma unroll
        for (int j = 0; j < 4; ++j) af[j] = LDA8O(j, 1);
        if (more) STAGE_A(t + 1, dn, 2);
        __builtin_amdgcn_s_barrier();
        __builtin_amdgcn_sched_barrier(0);
        PHASE_MFMA_O(0)
        __builtin_amdgcn_s_barrier();
        #pragma unroll
        for (int j = 0; j < 4; ++j) af[j] = LDA8O(4 + j, 1);
        if (more) STAGE_A(t + 1, dn, 3);
        __builtin_amdgcn_s_barrier();
        __builtin_amdgcn_sched_barrier(0);
        PHASE_MFMA_O(1)
        __builtin_amdgcn_s_barrier();
    }

    #pragma unroll
    for (int mf = 0; mf < 8; ++mf)
        #pragma unroll
        for (int r = 0; r < 4; ++r) {
            size_t rowg = (size_t)(m0 + wr * 128 + mf * 16 + quad * 4 + r);
            #pragma unroll
            for (int nf = 0; nf < 2; ++nf) {
                int colg = n0 + wc * 32 + nf * 16 + l15;
                outO[rowg * MODEL_DIM + colg] = acc[mf][nf][r] + bo[colg];
            }
        }
#undef STAGE_A
#undef STAGE_B
#undef LDA8O
#undef LDB8O
#undef PHASE_MFMA_O
}

// ------------------------------------------------------- flash attention (causal)
// grid (8,16,4); 256 thr = 4 waves; wave owns 32 q-rows of the active q-tile.
// Causal pair-balancing; T14 dbuf pipeline; T13 defer-max; T5 setprio; exp2.
__global__ __launch_bounds__(256, 2) void attn_k(const u16* __restrict__ Qb,
                                                 const u16* __restrict__ Kb,
                                                 const u32* __restrict__ VT32,
                                                 u16* __restrict__ Ob) {
    __shared__ __align__(16) u16 Ks[2][64 * 64];   // [key][dim], chunk-XOR swizzle
    __shared__ __align__(16) u16 Vs[2][64 * 64];   // [d][key],   chunk-XOR swizzle
    __shared__ __align__(16) u16 Pl[4 * 32 * 72];  // per-wave P^T [q][key], pad 8
    const int tid  = threadIdx.x;
    const int wave = tid >> 6, lane = tid & 63;
    const int l15  = lane & 15, quad = lane >> 4;
    const int j = blockIdx.x;                      // 0..7 pair index
    const int h = blockIdx.y, b = blockIdx.z;
    u16* pw = &Pl[wave * 32 * 72];

    const int key0 = tid >> 3;                     // 0..31
    const int c8   = (tid & 7) * 8;                // u16 units
    const int c4   = (tid & 7) * 4;                // u32 units (VT rows)
    const int lko  = key0 * 64 + (((tid & 7) ^ (key0 & 7)) * 8);   // LDS dst
    const u16* kgp = Kb + (size_t)(b * SEQ) * MODEL_DIM + h * HDIM;
    const u32* vgp = VT32 + (size_t)((b * NHEAD + h) * HDIM) * (SEQ / 2);

    int bufc = 0;                                  // buffer parity, spans passes
    for (int pp = 0; pp < 2; ++pp) {
        const int qt = pp ? j : 15 - j;            // heavy tile first
        const int q0 = qt * 128;
        const int qbase = q0 + wave * 32;

        short8 qfr[2][2];
        for (int qf = 0; qf < 2; ++qf)
            for (int ks = 0; ks < 2; ++ks)
                qfr[qf][ks] = *(const short8*)(Qb
                    + (size_t)(b * SEQ + qbase + qf * 16 + l15) * MODEL_DIM
                    + h * HDIM + ks * 32 + quad * 8);

        float m_i[2] = {-1e30f, -1e30f}, l_i[2] = {0.f, 0.f};
        f32x4 o_acc[4][2] = {};                    // [dt][qf]

        const int nkt = (q0 + 128) >> 6;
        uint4 kr0 = *(const uint4*)(kgp + (size_t)key0 * MODEL_DIM + c8);
        uint4 kr1 = *(const uint4*)(kgp + (size_t)(key0 + 32) * MODEL_DIM + c8);
        uint4 vr0 = *(const uint4*)(vgp + (size_t)key0 * (SEQ / 2) + c4);
        uint4 vr1 = *(const uint4*)(vgp + (size_t)(key0 + 32) * (SEQ / 2) + c4);

        for (int kt = 0; kt < nkt; ++kt) {
            const int k0 = kt * 64;
            u16* ksb = Ks[bufc];
            u16* vsb = Vs[bufc];
            *(uint4*)(&ksb[lko])        = kr0;
            *(uint4*)(&ksb[lko + 2048]) = kr1;
            *(uint4*)(&vsb[lko])        = vr0;
            *(uint4*)(&vsb[lko + 2048]) = vr1;
            __syncthreads();

            if (kt + 1 < nkt) {
                const int kn = k0 + 64;
                kr0 = *(const uint4*)(kgp + (size_t)(kn + key0) * MODEL_DIM + c8);
                kr1 = *(const uint4*)(kgp + (size_t)(kn + key0 + 32) * MODEL_DIM + c8);
                vr0 = *(const uint4*)(vgp + (size_t)key0 * (SEQ / 2) + (kn >> 1) + c4);
                vr1 = *(const uint4*)(vgp + (size_t)(key0 + 32) * (SEQ / 2)
                                      + (kn >> 1) + c4);
            }

            if (k0 <= qbase + 31) {
                f32x4 s[4][2] = {};
                for (int ks = 0; ks < 2; ++ks) {
                    short8 kfr[4];
                    for (int kf = 0; kf < 4; ++kf)
                        kfr[kf] = *(const short8*)(&ksb[(kf * 16 + l15) * 64
                                      + (((ks * 4 + quad) ^ (l15 & 7)) * 8)]);
                    __builtin_amdgcn_s_setprio(1);
                    for (int kf = 0; kf < 4; ++kf)
                        for (int qf = 0; qf < 2; ++qf)
                            s[kf][qf] = __builtin_amdgcn_mfma_f32_16x16x32_bf16(
                                            kfr[kf], qfr[qf][ks], s[kf][qf], 0, 0, 0);
                    __builtin_amdgcn_s_setprio(0);
                }
                for (int qf = 0; qf < 2; ++qf) {
                    int qg = qbase + qf * 16 + l15;
                    if (k0 + 63 > qbase + qf * 16) {
                        for (int kf = 0; kf < 4; ++kf)
                            for (int r = 0; r < 4; ++r)
                                if (k0 + kf * 16 + quad * 4 + r > qg)
                                    s[kf][qf][r] = -1e30f;
                    }
                    float t0 = fmaxf(fmaxf(s[0][qf][0], s[0][qf][1]),
                                     fmaxf(s[0][qf][2], s[0][qf][3]));
                    float t1 = fmaxf(fmaxf(s[1][qf][0], s[1][qf][1]),
                                     fmaxf(s[1][qf][2], s[1][qf][3]));
                    float t2 = fmaxf(fmaxf(s[2][qf][0], s[2][qf][1]),
                                     fmaxf(s[2][qf][2], s[2][qf][3]));
                    float t3 = fmaxf(fmaxf(s[3][qf][0], s[3][qf][1]),
                                     fmaxf(s[3][qf][2], s[3][qf][3]));
                    float rmax = fmaxf(fmaxf(t0, t1), fmaxf(t2, t3));
                    rmax = fmaxf(rmax, __shfl_xor(rmax, 16, 64));
                    rmax = fmaxf(rmax, __shfl_xor(rmax, 32, 64));
                    if (!__all(rmax <= m_i[qf] + 8.0f)) {
                        float mn = fmaxf(m_i[qf], rmax);
                        float alpha = exp2a(m_i[qf] - mn);
                        m_i[qf] = mn;
                        l_i[qf] *= alpha;
                        for (int dt = 0; dt < 4; ++dt)
                            for (int r = 0; r < 4; ++r) o_acc[dt][qf][r] *= alpha;
                    }
                    float mref = m_i[qf];
                    float psum = 0.f;
                    for (int kf = 0; kf < 4; ++kf)
                        for (int r = 0; r < 4; ++r) {
                            float p = exp2a(s[kf][qf][r] - mref);
                            s[kf][qf][r] = p;
                            psum += p;
                        }
                    psum += __shfl_xor(psum, 16, 64);
                    psum += __shfl_xor(psum, 32, 64);
                    l_i[qf] += psum;
                    for (int kf = 0; kf < 4; ++kf) {
                        uint2 w;
                        w.x = cvtpk(s[kf][qf][0], s[kf][qf][1]);
                        w.y = cvtpk(s[kf][qf][2], s[kf][qf][3]);
                        *(uint2*)(&pw[(qf * 16 + l15) * 72 + kf * 16 + quad * 4]) = w;
                    }
                }
                for (int ks = 0; ks < 2; ++ks) {
                    short8 pfr[2], vfr[4];
                    for (int qf = 0; qf < 2; ++qf)
                        pfr[qf] = *(const short8*)(&pw[(qf * 16 + l15) * 72
                                                       + ks * 32 + quad * 8]);
                    for (int dt = 0; dt < 4; ++dt)
                        vfr[dt] = *(const short8*)(&vsb[(dt * 16 + l15) * 64
                                      + (((ks * 4 + quad) ^ (l15 & 7)) * 8)]);
                    __builtin_amdgcn_s_setprio(1);
                    for (int dt = 0; dt < 4; ++dt)
                        for (int qf = 0; qf < 2; ++qf)
                            o_acc[dt][qf] = __builtin_amdgcn_mfma_f32_16x16x32_bf16(
                                                vfr[dt], pfr[qf], o_acc[dt][qf], 0, 0, 0);
                    __builtin_amdgcn_s_setprio(0);
                }
            }
            bufc ^= 1;
        }

        for (int qf = 0; qf < 2; ++qf) {
            float rl = 1.f / l_i[qf];
            int q = qbase + qf * 16 + l15;
            for (int dt = 0; dt < 4; ++dt) {
                uint2 w;
                w.x = cvtpk(o_acc[dt][qf][0] * rl, o_acc[dt][qf][1] * rl);
                w.y = cvtpk(o_acc[dt][qf][2] * rl, o_acc[dt][qf][3] * rl);
                *(uint2*)(&Ob[(size_t)(b * SEQ + q) * MODEL_DIM
                              + h * HDIM + dt * 16 + quad * 4]) = w;
            }
        }
    }
}

// --------------------------------------------------------------------- launcher
extern "C" void kernel_launch(void* const* d_in, const int* in_sizes, int n_in,
                              void* d_out, int out_size, void* d_ws, size_t ws_size,
                              hipStream_t stream) {
    const float* X  = (const float*)d_in[0];
    const float* Wq = (const float*)d_in[1];
    const float* bq = (const float*)d_in[2];
    const float* Wk = (const float*)d_in[3];
    const float* bk = (const float*)d_in[4];
    const float* Wv = (const float*)d_in[5];
    const float* bv = (const float*)d_in[6];
    const float* Wo = (const float*)d_in[7];
    const float* bo = (const float*)d_in[8];
    float* out = (float*)d_out;

    // ws: [Xb/Ob 16.78M][Wt 8.39M][Qb 16.78M][Kb 16.78M][unused][VT 16.78M]
    char* ws = (char*)d_ws;
    u16* Xb   = (u16*)ws;                       // aliased by Ob after QKV GEMM
    u16* Ob   = (u16*)ws;
    u16* Wt   = (u16*)(ws + 16777216);
    u16* Qb   = (u16*)(ws + 25165824);
    u16* Kb   = (u16*)(ws + 41943040);
    u32* VT32 = (u32*)(ws + 75497472);

    prep_k<<<dim3(12288), dim3(256), 0, stream>>>(X, Xb, Wq, Wk, Wv, Wo, Wt);
    gemm256qkv_k<<<dim3(32, 24), dim3(512), 0, stream>>>(Xb, Wt, Qb, Kb, VT32,
                                                         bq, bk, bv);
    attn_k<<<dim3(8, 16, 4), dim3(256), 0, stream>>>(Qb, Kb, VT32, Ob);
    gemm256o_k<<<dim3(32, 8), dim3(512), 0, stream>>>(Ob, Wt, out, bo);
}

// Round 15
// 255.197 us; speedup vs baseline: 1.4089x; 1.0039x over previous
//
#include <hip/hip_runtime.h>

typedef unsigned short u16;
typedef unsigned int   u32;
typedef __attribute__((ext_vector_type(4))) float f32x4;
typedef __attribute__((ext_vector_type(8))) short short8;

#define MODEL_DIM 1024
#define SEQ 2048
#define BATCH 4
#define NHEAD 16
#define HDIM 64
#define MTOT (BATCH*SEQ)                       /* 8192 */
#define ELEMS ((size_t)MTOT*MODEL_DIM)         /* 8388608 */

__device__ __forceinline__ u16 f2bf(float f) {
    u32 u = __float_as_uint(f);
    u = (u + 0x7fffu + ((u >> 16) & 1u)) >> 16;   // RNE
    return (u16)u;
}
__device__ __forceinline__ u32 pack2(float a, float b) {
    return (u32)f2bf(a) | ((u32)f2bf(b) << 16);
}
// packed RNE f32x2 -> bf16x2 (1 instr; no builtin on gfx950, T12 recipe)
__device__ __forceinline__ u32 cvtpk(float lo, float hi) {
    u32 r;
    asm("v_cvt_pk_bf16_f32 %0, %1, %2" : "=v"(r) : "v"(lo), "v"(hi));
    return r;
}
// raw 2^x (v_exp_f32); softmax runs in log2 domain (log2e folded into Q scale)
__device__ __forceinline__ float exp2a(float x) {
    float r;
    asm("v_exp_f32 %0, %1" : "=v"(r) : "v"(x));
    return r;
}

// async global->LDS 16B: wave-uniform LDS base + lane*16 (m97 pattern)
#define GLOAD16(g, l) __builtin_amdgcn_global_load_lds(                        \
        (const __attribute__((address_space(1))) unsigned int*)(g),            \
        (__attribute__((address_space(3))) unsigned int*)(l), 16, 0, 0)

// ------------------------- prep: cast X -> bf16  +  W[k][n] fp32 -> Wt[n][k] bf16
// flat grid: blocks [0, 8192) cast; blocks [8192, 12288) transpose W.
__global__ __launch_bounds__(256) void prep_k(const float* __restrict__ X,
                                              u16* __restrict__ Xb,
                                              const float* __restrict__ Wq,
                                              const float* __restrict__ Wk,
                                              const float* __restrict__ Wv,
                                              const float* __restrict__ Wo,
                                              u16* __restrict__ Wt) {
    const int bid = blockIdx.x, t = threadIdx.x;
    if (bid < 8192) {
        size_t i = ((size_t)bid * 256 + t) * 4;
        float4 v = *(const float4*)(X + i);
        uint2 o; o.x = pack2(v.x, v.y); o.y = pack2(v.z, v.w);
        *(uint2*)(Xb + i) = o;
        return;
    }
    __shared__ float tile[32][33];
    const int bid2 = bid - 8192;
    const int z = bid2 >> 10, rem = bid2 & 1023;
    const int by = rem >> 5, bx = rem & 31;
    const float* W = (z == 0) ? Wq : (z == 1) ? Wk : (z == 2) ? Wv : Wo;
    const int k0 = by * 32, n0 = bx * 32;
    const int x = t & 31, y = t >> 5;                   // 32 x 8
    for (int i = 0; i < 4; ++i)
        tile[y + i * 8][x] = W[(size_t)(k0 + y + i * 8) * MODEL_DIM + n0 + x];
    __syncthreads();
    u16* out = Wt + ((size_t)z << 20);
    for (int i = 0; i < 4; ++i)
        out[(size_t)(n0 + y + i * 8) * MODEL_DIM + k0 + x] = f2bf(tile[x][y + i * 8]);
}

// ------------------------------------------ QKV GEMM 256x128, 8-phase template
// Verified R14. grid (32,24) = 768 blocks = 3 full rounds/CU. acc[8][2]; 96KB.
__global__ __launch_bounds__(512) void gemm256qkv_k(
        const u16* __restrict__ A, const u16* __restrict__ Wt,
        u16* __restrict__ Qb, u16* __restrict__ Kb, u32* __restrict__ VT,
        const float* __restrict__ bq, const float* __restrict__ bk,
        const float* __restrict__ bv) {
    __shared__ __align__(16) u16 Ls[49152];        // 96KB: 2 buf x (A 32K + B 16K)
    const int tid  = threadIdx.x;
    const int wv   = tid >> 6, lane = tid & 63;
    const int l15  = lane & 15, quad = lane >> 4;
    const int wr = wv >> 2, wc = wv & 3;           // wave = (M-half, N-quarter/32)
    const int m0 = blockIdx.x * 256;
    const int region = blockIdx.y >> 3;            // 0=Q 1=K 2=V
    const int n0 = (blockIdx.y & 7) * 128;

    const u16* Ag = A + (size_t)m0 * MODEL_DIM;
    const u16* Bg = Wt + ((size_t)region << 20) + (size_t)n0 * MODEL_DIM;

    f32x4 acc[8][2] = {};

#define STAGE_A(kt, d, q) do {                                                 \
    const int kk0_ = (kt) * 64;                                                \
    int L_ = ((q) * 256 + wc * 64 + lane) * 16;                                \
    int P_ = L_ ^ (((L_ >> 7) & 7) << 4);                                      \
    GLOAD16(Ag + (size_t)(wr * 128 + (P_ >> 7)) * MODEL_DIM + kk0_             \
               + ((P_ & 127) >> 1),                                            \
            &Ls[(d) * 24576 + wr * 8192 + (L_ >> 1)]);                         \
} while (0)
#define STAGE_B(kt, d, q) do {                                                 \
    const int kk0_ = (kt) * 64;                                                \
    int L_ = ((q) * 512 + tid) * 16;                                           \
    int P_ = L_ ^ (((L_ >> 7) & 7) << 4);                                      \
    GLOAD16(Bg + (size_t)(P_ >> 7) * MODEL_DIM + kk0_ + ((P_ & 127) >> 1),     \
            &Ls[(d) * 24576 + 16384 + (L_ >> 1)]);                             \
} while (0)

#define LDA8Q(mf, ks) ({                                                       \
    int P_ = ((mf) * 16 + l15) * 128 + ((ks) * 4 + quad) * 16;                 \
    int L_ = P_ ^ (((P_ >> 7) & 7) << 4);                                      \
    *(const short8*)(ab + (L_ >> 1)); })
#define LDB8Q(nf, ks) ({                                                       \
    int P_ = (wc * 32 + (nf) * 16 + l15) * 128 + ((ks) * 4 + quad) * 16;       \
    int L_ = P_ ^ (((P_ >> 7) & 7) << 4);                                      \
    *(const short8*)(bbQ + (L_ >> 1)); })

#define PHASE_MFMA_Q(MH)                                                       \
    __builtin_amdgcn_s_setprio(1);                                             \
    _Pragma("unroll")                                                          \
    for (int j2 = 0; j2 < 4; ++j2)                                             \
        _Pragma("unroll")                                                      \
        for (int nf2 = 0; nf2 < 2; ++nf2)                                      \
            acc[(MH) * 4 + j2][nf2] = __builtin_amdgcn_mfma_f32_16x16x32_bf16( \
                af[j2], bf[nf2], acc[(MH) * 4 + j2][nf2], 0, 0, 0);            \
    __builtin_amdgcn_s_setprio(0);

    // prologue: tile 0 into buf 0 (6 gloads/thread)
    STAGE_A(0, 0, 0); STAGE_B(0, 0, 0);
    STAGE_A(0, 0, 1); STAGE_B(0, 0, 1);
    STAGE_A(0, 0, 2); STAGE_A(0, 0, 3);

    for (int t = 0; t < 16; ++t) {
        const int pp2 = t & 1;
        const u16* ab  = &Ls[pp2 * 24576 + wr * 8192];
        const u16* bbQ = &Ls[pp2 * 24576 + 16384];
        const int dn = pp2 ^ 1;
        const bool more = (t + 1) < 16;
        short8 af[4], bf[2];
        // ---- phase 0 (ks=0, mh=0): boundary — counted vmcnt, then publish
        if (more) { STAGE_A(t + 1, dn, 0); STAGE_B(t + 1, dn, 0); }
        if (more) asm volatile("s_waitcnt vmcnt(2)" ::: "memory");
        else      asm volatile("s_waitcnt vmcnt(0)" ::: "memory");
        __builtin_amdgcn_s_barrier();
        __builtin_amdgcn_sched_barrier(0);
        #pragma unroll
        for (int nf = 0; nf < 2; ++nf) bf[nf] = LDB8Q(nf, 0);
        #pragma unroll
        for (int j = 0; j < 4; ++j) af[j] = LDA8Q(j, 0);
        PHASE_MFMA_Q(0)
        __builtin_amdgcn_s_barrier();
        // ---- phase 1 (ks=0, mh=1)
        #pragma unroll
        for (int j = 0; j < 4; ++j) af[j] = LDA8Q(4 + j, 0);
        if (more) { STAGE_A(t + 1, dn, 1); STAGE_B(t + 1, dn, 1); }
        __builtin_amdgcn_s_barrier();
        __builtin_amdgcn_sched_barrier(0);
        PHASE_MFMA_Q(1)
        __builtin_amdgcn_s_barrier();
        // ---- phase 2 (ks=1, mh=0)
        #pragma unroll
        for (int nf = 0; nf < 2; ++nf) bf[nf] = LDB8Q(nf, 1);
        #pragma unroll
        for (int j = 0; j < 4; ++j) af[j] = LDA8Q(j, 1);
        if (more) STAGE_A(t + 1, dn, 2);
        __builtin_amdgcn_s_barrier();
        __builtin_amdgcn_sched_barrier(0);
        PHASE_MFMA_Q(0)
        __builtin_amdgcn_s_barrier();
        // ---- phase 3 (ks=1, mh=1)
        #pragma unroll
        for (int j = 0; j < 4; ++j) af[j] = LDA8Q(4 + j, 1);
        if (more) STAGE_A(t + 1, dn, 3);
        __builtin_amdgcn_s_barrier();
        __builtin_amdgcn_sched_barrier(0);
        PHASE_MFMA_Q(1)
        __builtin_amdgcn_s_barrier();
    }

    // ------------- epilogue (all acc loops unrolled — rule #20)
    if (region < 2) {
        const float* bias = region ? bk : bq;
        u16* dst = region ? Kb : Qb;
        const float qsc = region ? 1.0f : 0.125f * 1.44269504f;
        const float cfr = -0.017989922f;               // -ln(10000)/512
        float invf[2];
        #pragma unroll
        for (int nf = 0; nf < 2; ++nf) {
            int c = n0 + wc * 32 + nf * 16 + l15;
            invf[nf] = __expf((float)(c >> 1) * cfr);
        }
        const float sgn = (l15 & 1) ? 1.0f : -1.0f;    // even: x1*cs - x2*sn
        #pragma unroll
        for (int mf = 0; mf < 8; ++mf)
            #pragma unroll
            for (int r = 0; r < 4; ++r) {
                size_t rowg = (size_t)(m0 + wr * 128 + mf * 16 + quad * 4 + r);
                float fs = (float)(int)(rowg & 2047);
                #pragma unroll
                for (int nf = 0; nf < 2; ++nf) {
                    int c = n0 + wc * 32 + nf * 16 + l15;
                    float v = acc[mf][nf][r] + bias[c];
                    float mate = __shfl_xor(v, 1, 64);
                    float sn, cs;
                    __sincosf(fs * invf[nf], &sn, &cs);
                    float o = (v * cs + sgn * mate * sn) * qsc;
                    dst[rowg * MODEL_DIM + c] = f2bf(o);
                }
            }
    } else {
        // V: pack + store V^T (VT32) directly from acc (R9-proven pattern)
        const int b_ = m0 >> 11;
        const int s0 = m0 & 2047;
        #pragma unroll
        for (int nf = 0; nf < 2; ++nf) {
            int c = n0 + wc * 32 + nf * 16 + l15;
            float bvc = bv[c];
            u32* vtrow = VT + (size_t)((b_ * NHEAD + (c >> 6)) * HDIM
                                       + (c & 63)) * (SEQ / 2);
            #pragma unroll
            for (int mf = 0; mf < 8; ++mf) {
                int sb2 = s0 + wr * 128 + mf * 16 + quad * 4;
                uint2 w;
                w.x = cvtpk(acc[mf][nf][0] + bvc, acc[mf][nf][1] + bvc);
                w.y = cvtpk(acc[mf][nf][2] + bvc, acc[mf][nf][3] + bvc);
                *(uint2*)(vtrow + (sb2 >> 1)) = w;
            }
        }
    }
#undef STAGE_A
#undef STAGE_B
#undef LDA8Q
#undef LDB8Q
#undef PHASE_MFMA_Q
}

// ------------------------------------------------ O-proj GEMM 256x128, 8-phase
// Verified R12. grid (32,8) = 256 blocks = 1/CU. acc[8][2]; LDS 96KB.
__global__ __launch_bounds__(512) void gemm256o_k(
        const u16* __restrict__ A, const u16* __restrict__ Wt,
        float* __restrict__ outO, const float* __restrict__ bo) {
    __shared__ __align__(16) u16 Ls[49152];        // 96KB: 2 buf x (A 32K + B 16K)
    const int tid  = threadIdx.x;
    const int wv   = tid >> 6, lane = tid & 63;
    const int l15  = lane & 15, quad = lane >> 4;
    const int wr = wv >> 2, wc = wv & 3;           // wave = (M-half, N-quarter/32)
    const int m0 = blockIdx.x * 256;
    const int n0 = blockIdx.y * 128;

    const u16* Ag = A + (size_t)m0 * MODEL_DIM;
    const u16* Bg = Wt + ((size_t)3 << 20) + (size_t)n0 * MODEL_DIM;

    f32x4 acc[8][2] = {};

#define STAGE_A(kt, d, q) do {                                                 \
    const int kk0_ = (kt) * 64;                                                \
    int L_ = ((q) * 256 + wc * 64 + lane) * 16;                                \
    int P_ = L_ ^ (((L_ >> 7) & 7) << 4);                                      \
    GLOAD16(Ag + (size_t)(wr * 128 + (P_ >> 7)) * MODEL_DIM + kk0_             \
               + ((P_ & 127) >> 1),                                            \
            &Ls[(d) * 24576 + wr * 8192 + (L_ >> 1)]);                         \
} while (0)
#define STAGE_B(kt, d, q) do {                                                 \
    const int kk0_ = (kt) * 64;                                                \
    int L_ = ((q) * 512 + tid) * 16;                                           \
    int P_ = L_ ^ (((L_ >> 7) & 7) << 4);                                      \
    GLOAD16(Bg + (size_t)(P_ >> 7) * MODEL_DIM + kk0_ + ((P_ & 127) >> 1),     \
            &Ls[(d) * 24576 + 16384 + (L_ >> 1)]);                             \
} while (0)

#define LDA8O(mf, ks) ({                                                       \
    int P_ = ((mf) * 16 + l15) * 128 + ((ks) * 4 + quad) * 16;                 \
    int L_ = P_ ^ (((P_ >> 7) & 7) << 4);                                      \
    *(const short8*)(ab + (L_ >> 1)); })
#define LDB8O(nf, ks) ({                                                       \
    int P_ = (wc * 32 + (nf) * 16 + l15) * 128 + ((ks) * 4 + quad) * 16;       \
    int L_ = P_ ^ (((P_ >> 7) & 7) << 4);                                      \
    *(const short8*)(bbO + (L_ >> 1)); })

#define PHASE_MFMA_O(MH)                                                       \
    __builtin_amdgcn_s_setprio(1);                                             \
    _Pragma("unroll")                                                          \
    for (int j2 = 0; j2 < 4; ++j2)                                             \
        _Pragma("unroll")                                                      \
        for (int nf2 = 0; nf2 < 2; ++nf2)                                      \
            acc[(MH) * 4 + j2][nf2] = __builtin_amdgcn_mfma_f32_16x16x32_bf16( \
                af[j2], bf[nf2], acc[(MH) * 4 + j2][nf2], 0, 0, 0);            \
    __builtin_amdgcn_s_setprio(0);

    STAGE_A(0, 0, 0); STAGE_B(0, 0, 0);
    STAGE_A(0, 0, 1); STAGE_B(0, 0, 1);
    STAGE_A(0, 0, 2); STAGE_A(0, 0, 3);

    for (int t = 0; t < 16; ++t) {
        const int pp2 = t & 1;
        const u16* ab  = &Ls[pp2 * 24576 + wr * 8192];
        const u16* bbO = &Ls[pp2 * 24576 + 16384];
        const int dn = pp2 ^ 1;
        const bool more = (t + 1) < 16;
        short8 af[4], bf[2];
        if (more) { STAGE_A(t + 1, dn, 0); STAGE_B(t + 1, dn, 0); }
        if (more) asm volatile("s_waitcnt vmcnt(2)" ::: "memory");
        else      asm volatile("s_waitcnt vmcnt(0)" ::: "memory");
        __builtin_amdgcn_s_barrier();
        __builtin_amdgcn_sched_barrier(0);
        #pragma unroll
        for (int nf = 0; nf < 2; ++nf) bf[nf] = LDB8O(nf, 0);
        #pragma unroll
        for (int j = 0; j < 4; ++j) af[j] = LDA8O(j, 0);
        PHASE_MFMA_O(0)
        __builtin_amdgcn_s_barrier();
        #pragma unroll
        for (int j = 0; j < 4; ++j) af[j] = LDA8O(4 + j, 0);
        if (more) { STAGE_A(t + 1, dn, 1); STAGE_B(t + 1, dn, 1); }
        __builtin_amdgcn_s_barrier();
        __builtin_amdgcn_sched_barrier(0);
        PHASE_MFMA_O(1)
        __builtin_amdgcn_s_barrier();
        #pragma unroll
        for (int nf = 0; nf < 2; ++nf) bf[nf] = LDB8O(nf, 1);
        #pragma unroll
        for (int j = 0; j < 4; ++j) af[j] = LDA8O(j, 1);
        if (more) STAGE_A(t + 1, dn, 2);
        __builtin_amdgcn_s_barrier();
        __builtin_amdgcn_sched_barrier(0);
        PHASE_MFMA_O(0)
        __builtin_amdgcn_s_barrier();
        #pragma unroll
        for (int j = 0; j < 4; ++j) af[j] = LDA8O(4 + j, 1);
        if (more) STAGE_A(t + 1, dn, 3);
        __builtin_amdgcn_s_barrier();
        __builtin_amdgcn_sched_barrier(0);
        PHASE_MFMA_O(1)
        __builtin_amdgcn_s_barrier();
    }

    #pragma unroll
    for (int mf = 0; mf < 8; ++mf)
        #pragma unroll
        for (int r = 0; r < 4; ++r) {
            size_t rowg = (size_t)(m0 + wr * 128 + mf * 16 + quad * 4 + r);
            #pragma unroll
            for (int nf = 0; nf < 2; ++nf) {
                int colg = n0 + wc * 32 + nf * 16 + l15;
                outO[rowg * MODEL_DIM + colg] = acc[mf][nf][r] + bo[colg];
            }
        }
#undef STAGE_A
#undef STAGE_B
#undef LDA8O
#undef LDB8O
#undef PHASE_MFMA_O
}

// ------------------------------------------------------- flash attention (causal)
// R15: 512 thr = 8 waves; wave owns 16 q-rows (one 16-row fragment) of the
// active q-tile -> 16 waves/CU at 2 blocks/CU (was 8) for 2x latency hiding.
// Same pair-balancing, T14 dbuf pipeline (staging now exactly 1 uint4/thread
// per buffer), T13 defer-max, T5 setprio, exp2-domain softmax.
__global__ __launch_bounds__(512, 2) void attn_k(const u16* __restrict__ Qb,
                                                 const u16* __restrict__ Kb,
                                                 const u32* __restrict__ VT32,
                                                 u16* __restrict__ Ob) {
    __shared__ __align__(16) u16 Ks[2][64 * 64];   // [key][dim], chunk-XOR swizzle
    __shared__ __align__(16) u16 Vs[2][64 * 64];   // [d][key],   chunk-XOR swizzle
    __shared__ __align__(16) u16 Pl[8 * 16 * 72];  // per-wave P^T [q][key], pad 8
    const int tid  = threadIdx.x;
    const int wave = tid >> 6, lane = tid & 63;
    const int l15  = lane & 15, quad = lane >> 4;
    const int j = blockIdx.x;                      // 0..7 pair index
    const int h = blockIdx.y, b = blockIdx.z;
    u16* pw = &Pl[wave * 16 * 72];

    // staging geometry: 512 thr x 16B = one full 64x64 bf16 tile per pass
    const int key0 = tid >> 3;                     // 0..63
    const int c8   = (tid & 7) * 8;                // u16 units
    const int c4   = (tid & 7) * 4;                // u32 units (VT rows)
    const int lko  = key0 * 64 + (((tid & 7) ^ (key0 & 7)) * 8);   // LDS dst
    const u16* kgp = Kb + (size_t)(b * SEQ) * MODEL_DIM + h * HDIM;
    const u32* vgp = VT32 + (size_t)((b * NHEAD + h) * HDIM) * (SEQ / 2);

    int bufc = 0;                                  // buffer parity, spans passes
    for (int pp = 0; pp < 2; ++pp) {
        const int qt = pp ? j : 15 - j;            // heavy tile first
        const int q0 = qt * 128;
        const int qbase = q0 + wave * 16;          // this wave's 16 q-rows

        // Q B-frags (n=q=l15, k=dim=quad*8+jj), pre-scaled 0.125*log2e
        short8 qfr[2];
        for (int ks = 0; ks < 2; ++ks)
            qfr[ks] = *(const short8*)(Qb
                + (size_t)(b * SEQ + qbase + l15) * MODEL_DIM
                + h * HDIM + ks * 32 + quad * 8);

        float m_i = -1e30f, l_i = 0.f;
        f32x4 o_acc[4] = {};                       // [dt]

        const int nkt = (q0 + 128) >> 6;
        // prologue prefetch (kt = 0): 1 uint4 each for K and V^T
        uint4 kr0 = *(const uint4*)(kgp + (size_t)key0 * MODEL_DIM + c8);
        uint4 vr0 = *(const uint4*)(vgp + (size_t)key0 * (SEQ / 2) + c4);

        for (int kt = 0; kt < nkt; ++kt) {
            const int k0 = kt * 64;
            u16* ksb = Ks[bufc];
            u16* vsb = Vs[bufc];
            *(uint4*)(&ksb[lko]) = kr0;            // drain prefetched tile -> LDS
            *(uint4*)(&vsb[lko]) = vr0;
            __syncthreads();                       // single barrier per iter

            if (kt + 1 < nkt) {                    // prefetch next tile (hidden
                const int kn = k0 + 64;            //  under this tile's compute)
                kr0 = *(const uint4*)(kgp + (size_t)(kn + key0) * MODEL_DIM + c8);
                vr0 = *(const uint4*)(vgp + (size_t)key0 * (SEQ / 2) + (kn >> 1) + c4);
            }

            if (k0 <= qbase + 15) {                // wave has live rows this tile
                // S^T = K Q^T
                f32x4 s[4] = {};
                for (int ks = 0; ks < 2; ++ks) {
                    short8 kfr[4];
                    for (int kf = 0; kf < 4; ++kf)
                        kfr[kf] = *(const short8*)(&ksb[(kf * 16 + l15) * 64
                                      + (((ks * 4 + quad) ^ (l15 & 7)) * 8)]);
                    __builtin_amdgcn_s_setprio(1);
                    for (int kf = 0; kf < 4; ++kf)
                        s[kf] = __builtin_amdgcn_mfma_f32_16x16x32_bf16(
                                    kfr[kf], qfr[ks], s[kf], 0, 0, 0);
                    __builtin_amdgcn_s_setprio(0);
                }
                const int qg = qbase + l15;
                if (k0 + 63 > qbase) {             // diagonal tile: apply mask
                    for (int kf = 0; kf < 4; ++kf)
                        for (int r = 0; r < 4; ++r)
                            if (k0 + kf * 16 + quad * 4 + r > qg)
                                s[kf][r] = -1e30f;
                }
                // max via fmaxf triples (v_max3 fusion)
                float t0 = fmaxf(fmaxf(s[0][0], s[0][1]), fmaxf(s[0][2], s[0][3]));
                float t1 = fmaxf(fmaxf(s[1][0], s[1][1]), fmaxf(s[1][2], s[1][3]));
                float t2 = fmaxf(fmaxf(s[2][0], s[2][1]), fmaxf(s[2][2], s[2][3]));
                float t3 = fmaxf(fmaxf(s[3][0], s[3][1]), fmaxf(s[3][2], s[3][3]));
                float rmax = fmaxf(fmaxf(t0, t1), fmaxf(t2, t3));
                rmax = fmaxf(rmax, __shfl_xor(rmax, 16, 64));
                rmax = fmaxf(rmax, __shfl_xor(rmax, 32, 64));
                // T13 defer-max: skip rescale unless some row grew > +8
                if (!__all(rmax <= m_i + 8.0f)) {
                    float mn = fmaxf(m_i, rmax);
                    float alpha = exp2a(m_i - mn);
                    m_i = mn;
                    l_i *= alpha;
                    for (int dt = 0; dt < 4; ++dt)
                        for (int r = 0; r < 4; ++r) o_acc[dt][r] *= alpha;
                }
                float psum = 0.f;
                for (int kf = 0; kf < 4; ++kf)
                    for (int r = 0; r < 4; ++r) {
                        float p = exp2a(s[kf][r] - m_i);
                        s[kf][r] = p;
                        psum += p;
                    }
                psum += __shfl_xor(psum, 16, 64);
                psum += __shfl_xor(psum, 32, 64);
                l_i += psum;
                for (int kf = 0; kf < 4; ++kf) {   // P^T -> LDS (uint2)
                    uint2 w;
                    w.x = cvtpk(s[kf][0], s[kf][1]);
                    w.y = cvtpk(s[kf][2], s[kf][3]);
                    *(uint2*)(&pw[l15 * 72 + kf * 16 + quad * 4]) = w;
                }
                // O^T += V^T P^T
                for (int ks = 0; ks < 2; ++ks) {
                    short8 pfr, vfr[4];
                    pfr = *(const short8*)(&pw[l15 * 72 + ks * 32 + quad * 8]);
                    for (int dt = 0; dt < 4; ++dt)
                        vfr[dt] = *(const short8*)(&vsb[(dt * 16 + l15) * 64
                                      + (((ks * 4 + quad) ^ (l15 & 7)) * 8)]);
                    __builtin_amdgcn_s_setprio(1);
                    for (int dt = 0; dt < 4; ++dt)
                        o_acc[dt] = __builtin_amdgcn_mfma_f32_16x16x32_bf16(
                                        vfr[dt], pfr, o_acc[dt], 0, 0, 0);
                    __builtin_amdgcn_s_setprio(0);
                }
            }
            bufc ^= 1;
        }

        // O^T C-layout: q = l15, d = quad*4+r (within dt)
        {
            float rl = 1.f / l_i;
            int q = qbase + l15;
            for (int dt = 0; dt < 4; ++dt) {
                uint2 w;
                w.x = cvtpk(o_acc[dt][0] * rl, o_acc[dt][1] * rl);
                w.y = cvtpk(o_acc[dt][2] * rl, o_acc[dt][3] * rl);
                *(uint2*)(&Ob[(size_t)(b * SEQ + q) * MODEL_DIM
                              + h * HDIM + dt * 16 + quad * 4]) = w;
            }
        }
    }
}

// --------------------------------------------------------------------- launcher
extern "C" void kernel_launch(void* const* d_in, const int* in_sizes, int n_in,
                              void* d_out, int out_size, void* d_ws, size_t ws_size,
                              hipStream_t stream) {
    const float* X  = (const float*)d_in[0];
    const float* Wq = (const float*)d_in[1];
    const float* bq = (const float*)d_in[2];
    const float* Wk = (const float*)d_in[3];
    const float* bk = (const float*)d_in[4];
    const float* Wv = (const float*)d_in[5];
    const float* bv = (const float*)d_in[6];
    const float* Wo = (const float*)d_in[7];
    const float* bo = (const float*)d_in[8];
    float* out = (float*)d_out;

    // ws: [Xb/Ob 16.78M][Wt 8.39M][Qb 16.78M][Kb 16.78M][unused][VT 16.78M]
    char* ws = (char*)d_ws;
    u16* Xb   = (u16*)ws;                       // aliased by Ob after QKV GEMM
    u16* Ob   = (u16*)ws;
    u16* Wt   = (u16*)(ws + 16777216);
    u16* Qb   = (u16*)(ws + 25165824);
    u16* Kb   = (u16*)(ws + 41943040);
    u32* VT32 = (u32*)(ws + 75497472);

    prep_k<<<dim3(12288), dim3(256), 0, stream>>>(X, Xb, Wq, Wk, Wv, Wo, Wt);
    gemm256qkv_k<<<dim3(32, 24), dim3(512), 0, stream>>>(Xb, Wt, Qb, Kb, VT32,
                                                         bq, bk, bv);
    attn_k<<<dim3(8, 16, 4), dim3(512), 0, stream>>>(Qb, Kb, VT32, Ob);
    gemm256o_k<<<dim3(32, 8), dim3(512), 0, stream>>>(Ob, Wt, out, bo);
}

// Round 16
// 250.123 us; speedup vs baseline: 1.4375x; 1.0203x over previous
//
#include <hip/hip_runtime.h>

typedef unsigned short u16;
typedef unsigned int   u32;
typedef __attribute__((ext_vector_type(4))) float f32x4;
typedef __attribute__((ext_vector_type(8))) short short8;

#define MODEL_DIM 1024
#define SEQ 2048
#define BATCH 4
#define NHEAD 16
#define HDIM 64
#define MTOT (BATCH*SEQ)                       /* 8192 */
#define ELEMS ((size_t)MTOT*MODEL_DIM)         /* 8388608 */

__device__ __forceinline__ u16 f2bf(float f) {
    u32 u = __float_as_uint(f);
    u = (u + 0x7fffu + ((u >> 16) & 1u)) >> 16;   // RNE
    return (u16)u;
}
__device__ __forceinline__ u32 pack2(float a, float b) {
    return (u32)f2bf(a) | ((u32)f2bf(b) << 16);
}
// packed RNE f32x2 -> bf16x2 (1 instr; no builtin on gfx950, T12 recipe)
__device__ __forceinline__ u32 cvtpk(float lo, float hi) {
    u32 r;
    asm("v_cvt_pk_bf16_f32 %0, %1, %2" : "=v"(r) : "v"(lo), "v"(hi));
    return r;
}
// raw 2^x (v_exp_f32); softmax runs in log2 domain (log2e folded into Q scale)
__device__ __forceinline__ float exp2a(float x) {
    float r;
    asm("v_exp_f32 %0, %1" : "=v"(r) : "v"(x));
    return r;
}

// async global->LDS 16B: wave-uniform LDS base + lane*16 (m97 pattern)
#define GLOAD16(g, l) __builtin_amdgcn_global_load_lds(                        \
        (const __attribute__((address_space(1))) unsigned int*)(g),            \
        (__attribute__((address_space(3))) unsigned int*)(l), 16, 0, 0)

// ------------------------- prep: cast X -> bf16  +  W[k][n] fp32 -> Wt[n][k] bf16
// flat grid: blocks [0, 8192) cast; blocks [8192, 12288) transpose W.
__global__ __launch_bounds__(256) void prep_k(const float* __restrict__ X,
                                              u16* __restrict__ Xb,
                                              const float* __restrict__ Wq,
                                              const float* __restrict__ Wk,
                                              const float* __restrict__ Wv,
                                              const float* __restrict__ Wo,
                                              u16* __restrict__ Wt) {
    const int bid = blockIdx.x, t = threadIdx.x;
    if (bid < 8192) {
        size_t i = ((size_t)bid * 256 + t) * 4;
        float4 v = *(const float4*)(X + i);
        uint2 o; o.x = pack2(v.x, v.y); o.y = pack2(v.z, v.w);
        *(uint2*)(Xb + i) = o;
        return;
    }
    __shared__ float tile[32][33];
    const int bid2 = bid - 8192;
    const int z = bid2 >> 10, rem = bid2 & 1023;
    const int by = rem >> 5, bx = rem & 31;
    const float* W = (z == 0) ? Wq : (z == 1) ? Wk : (z == 2) ? Wv : Wo;
    const int k0 = by * 32, n0 = bx * 32;
    const int x = t & 31, y = t >> 5;                   // 32 x 8
    for (int i = 0; i < 4; ++i)
        tile[y + i * 8][x] = W[(size_t)(k0 + y + i * 8) * MODEL_DIM + n0 + x];
    __syncthreads();
    u16* out = Wt + ((size_t)z << 20);
    for (int i = 0; i < 4; ++i)
        out[(size_t)(n0 + y + i * 8) * MODEL_DIM + k0 + x] = f2bf(tile[x][y + i * 8]);
}

// ------------------------------------------ QKV GEMM 256x128, 2-phase template
// R16: merged mh-phases -> 2 phases/K-tile (4 barriers vs 8). At 1 block/CU
// (2 waves/SIMD) the 8-phase's per-phase 8-MFMA clusters left MfmaUtil at 28%;
// 16-MFMA clusters amortize the barrier pacing. Staging 3+3 loads across the
// two phases; boundary vmcnt(3) drains the prior tile's 6 loads (same
// invariant algebra as the R12-verified vmcnt(2)/4-load scheme). Accumulation
// order per acc unchanged (ks0 then ks1) -> bitwise-identical output.
__global__ __launch_bounds__(512) void gemm256qkv_k(
        const u16* __restrict__ A, const u16* __restrict__ Wt,
        u16* __restrict__ Qb, u16* __restrict__ Kb, u32* __restrict__ VT,
        const float* __restrict__ bq, const float* __restrict__ bk,
        const float* __restrict__ bv) {
    __shared__ __align__(16) u16 Ls[49152];        // 96KB: 2 buf x (A 32K + B 16K)
    const int tid  = threadIdx.x;
    const int wv   = tid >> 6, lane = tid & 63;
    const int l15  = lane & 15, quad = lane >> 4;
    const int wr = wv >> 2, wc = wv & 3;           // wave = (M-half, N-quarter/32)
    const int m0 = blockIdx.x * 256;
    const int region = blockIdx.y >> 3;            // 0=Q 1=K 2=V
    const int n0 = (blockIdx.y & 7) * 128;

    const u16* Ag = A + (size_t)m0 * MODEL_DIM;
    const u16* Bg = Wt + ((size_t)region << 20) + (size_t)n0 * MODEL_DIM;

    f32x4 acc[8][2] = {};

#define STAGE_A(kt, d, q) do {                                                 \
    const int kk0_ = (kt) * 64;                                                \
    int L_ = ((q) * 256 + wc * 64 + lane) * 16;                                \
    int P_ = L_ ^ (((L_ >> 7) & 7) << 4);                                      \
    GLOAD16(Ag + (size_t)(wr * 128 + (P_ >> 7)) * MODEL_DIM + kk0_             \
               + ((P_ & 127) >> 1),                                            \
            &Ls[(d) * 24576 + wr * 8192 + (L_ >> 1)]);                         \
} while (0)
#define STAGE_B(kt, d, q) do {                                                 \
    const int kk0_ = (kt) * 64;                                                \
    int L_ = ((q) * 512 + tid) * 16;                                           \
    int P_ = L_ ^ (((L_ >> 7) & 7) << 4);                                      \
    GLOAD16(Bg + (size_t)(P_ >> 7) * MODEL_DIM + kk0_ + ((P_ & 127) >> 1),     \
            &Ls[(d) * 24576 + 16384 + (L_ >> 1)]);                             \
} while (0)

#define LDA8Q(mf, ks) ({                                                       \
    int P_ = ((mf) * 16 + l15) * 128 + ((ks) * 4 + quad) * 16;                 \
    int L_ = P_ ^ (((P_ >> 7) & 7) << 4);                                      \
    *(const short8*)(ab + (L_ >> 1)); })
#define LDB8Q(nf, ks) ({                                                       \
    int P_ = (wc * 32 + (nf) * 16 + l15) * 128 + ((ks) * 4 + quad) * 16;       \
    int L_ = P_ ^ (((P_ >> 7) & 7) << 4);                                      \
    *(const short8*)(bbQ + (L_ >> 1)); })

    // prologue: tile 0 into buf 0 (6 gloads/thread)
    STAGE_A(0, 0, 0); STAGE_B(0, 0, 0);
    STAGE_A(0, 0, 1); STAGE_B(0, 0, 1);
    STAGE_A(0, 0, 2); STAGE_A(0, 0, 3);

    for (int t = 0; t < 16; ++t) {
        const int pp2 = t & 1;
        const u16* ab  = &Ls[pp2 * 24576 + wr * 8192];
        const u16* bbQ = &Ls[pp2 * 24576 + 16384];
        const int dn = pp2 ^ 1;
        const bool more = (t + 1) < 16;
        short8 af[8], bf[2];
        // ---- phase A (ks=0): boundary — counted vmcnt, publish, 16 MFMA
        if (more) { STAGE_A(t + 1, dn, 0); STAGE_B(t + 1, dn, 0);
                    STAGE_A(t + 1, dn, 1); }
        if (more) asm volatile("s_waitcnt vmcnt(3)" ::: "memory");
        else      asm volatile("s_waitcnt vmcnt(0)" ::: "memory");
        __builtin_amdgcn_s_barrier();
        __builtin_amdgcn_sched_barrier(0);
        #pragma unroll
        for (int nf = 0; nf < 2; ++nf) bf[nf] = LDB8Q(nf, 0);
        #pragma unroll
        for (int j = 0; j < 8; ++j) af[j] = LDA8Q(j, 0);
        __builtin_amdgcn_s_setprio(1);
        #pragma unroll
        for (int j2 = 0; j2 < 8; ++j2)
            #pragma unroll
            for (int nf2 = 0; nf2 < 2; ++nf2)
                acc[j2][nf2] = __builtin_amdgcn_mfma_f32_16x16x32_bf16(
                                   af[j2], bf[nf2], acc[j2][nf2], 0, 0, 0);
        __builtin_amdgcn_s_setprio(0);
        __builtin_amdgcn_s_barrier();
        // ---- phase B (ks=1): ds_reads first, stage, barrier, 16 MFMA
        #pragma unroll
        for (int nf = 0; nf < 2; ++nf) bf[nf] = LDB8Q(nf, 1);
        #pragma unroll
        for (int j = 0; j < 8; ++j) af[j] = LDA8Q(j, 1);
        if (more) { STAGE_B(t + 1, dn, 1); STAGE_A(t + 1, dn, 2);
                    STAGE_A(t + 1, dn, 3); }
        __builtin_amdgcn_s_barrier();
        __builtin_amdgcn_sched_barrier(0);
        __builtin_amdgcn_s_setprio(1);
        #pragma unroll
        for (int j2 = 0; j2 < 8; ++j2)
            #pragma unroll
            for (int nf2 = 0; nf2 < 2; ++nf2)
                acc[j2][nf2] = __builtin_amdgcn_mfma_f32_16x16x32_bf16(
                                   af[j2], bf[nf2], acc[j2][nf2], 0, 0, 0);
        __builtin_amdgcn_s_setprio(0);
        __builtin_amdgcn_s_barrier();
    }

    // ------------- epilogue (all acc loops unrolled — rule #20)
    if (region < 2) {
        const float* bias = region ? bk : bq;
        u16* dst = region ? Kb : Qb;
        const float qsc = region ? 1.0f : 0.125f * 1.44269504f;
        const float cfr = -0.017989922f;               // -ln(10000)/512
        float invf[2];
        #pragma unroll
        for (int nf = 0; nf < 2; ++nf) {
            int c = n0 + wc * 32 + nf * 16 + l15;
            invf[nf] = __expf((float)(c >> 1) * cfr);
        }
        const float sgn = (l15 & 1) ? 1.0f : -1.0f;    // even: x1*cs - x2*sn
        #pragma unroll
        for (int mf = 0; mf < 8; ++mf)
            #pragma unroll
            for (int r = 0; r < 4; ++r) {
                size_t rowg = (size_t)(m0 + wr * 128 + mf * 16 + quad * 4 + r);
                float fs = (float)(int)(rowg & 2047);
                #pragma unroll
                for (int nf = 0; nf < 2; ++nf) {
                    int c = n0 + wc * 32 + nf * 16 + l15;
                    float v = acc[mf][nf][r] + bias[c];
                    float mate = __shfl_xor(v, 1, 64);
                    float sn, cs;
                    __sincosf(fs * invf[nf], &sn, &cs);
                    float o = (v * cs + sgn * mate * sn) * qsc;
                    dst[rowg * MODEL_DIM + c] = f2bf(o);
                }
            }
    } else {
        // V: pack + store V^T (VT32) directly from acc (R9-proven pattern)
        const int b_ = m0 >> 11;
        const int s0 = m0 & 2047;
        #pragma unroll
        for (int nf = 0; nf < 2; ++nf) {
            int c = n0 + wc * 32 + nf * 16 + l15;
            float bvc = bv[c];
            u32* vtrow = VT + (size_t)((b_ * NHEAD + (c >> 6)) * HDIM
                                       + (c & 63)) * (SEQ / 2);
            #pragma unroll
            for (int mf = 0; mf < 8; ++mf) {
                int sb2 = s0 + wr * 128 + mf * 16 + quad * 4;
                uint2 w;
                w.x = cvtpk(acc[mf][nf][0] + bvc, acc[mf][nf][1] + bvc);
                w.y = cvtpk(acc[mf][nf][2] + bvc, acc[mf][nf][3] + bvc);
                *(uint2*)(vtrow + (sb2 >> 1)) = w;
            }
        }
    }
#undef STAGE_A
#undef STAGE_B
#undef LDA8Q
#undef LDB8Q
}

// ------------------------------------------------ O-proj GEMM 256x128, 8-phase
// Verified R12. grid (32,8) = 256 blocks = 1/CU. acc[8][2]; LDS 96KB.
__global__ __launch_bounds__(512) void gemm256o_k(
        const u16* __restrict__ A, const u16* __restrict__ Wt,
        float* __restrict__ outO, const float* __restrict__ bo) {
    __shared__ __align__(16) u16 Ls[49152];        // 96KB: 2 buf x (A 32K + B 16K)
    const int tid  = threadIdx.x;
    const int wv   = tid >> 6, lane = tid & 63;
    const int l15  = lane & 15, quad = lane >> 4;
    const int wr = wv >> 2, wc = wv & 3;           // wave = (M-half, N-quarter/32)
    const int m0 = blockIdx.x * 256;
    const int n0 = blockIdx.y * 128;

    const u16* Ag = A + (size_t)m0 * MODEL_DIM;
    const u16* Bg = Wt + ((size_t)3 << 20) + (size_t)n0 * MODEL_DIM;

    f32x4 acc[8][2] = {};

#define STAGE_A(kt, d, q) do {                                                 \
    const int kk0_ = (kt) * 64;                                                \
    int L_ = ((q) * 256 + wc * 64 + lane) * 16;                                \
    int P_ = L_ ^ (((L_ >> 7) & 7) << 4);                                      \
    GLOAD16(Ag + (size_t)(wr * 128 + (P_ >> 7)) * MODEL_DIM + kk0_             \
               + ((P_ & 127) >> 1),                                            \
            &Ls[(d) * 24576 + wr * 8192 + (L_ >> 1)]);                         \
} while (0)
#define STAGE_B(kt, d, q) do {                                                 \
    const int kk0_ = (kt) * 64;                                                \
    int L_ = ((q) * 512 + tid) * 16;                                           \
    int P_ = L_ ^ (((L_ >> 7) & 7) << 4);                                      \
    GLOAD16(Bg + (size_t)(P_ >> 7) * MODEL_DIM + kk0_ + ((P_ & 127) >> 1),     \
            &Ls[(d) * 24576 + 16384 + (L_ >> 1)]);                             \
} while (0)

#define LDA8O(mf, ks) ({                                                       \
    int P_ = ((mf) * 16 + l15) * 128 + ((ks) * 4 + quad) * 16;                 \
    int L_ = P_ ^ (((P_ >> 7) & 7) << 4);                                      \
    *(const short8*)(ab + (L_ >> 1)); })
#define LDB8O(nf, ks) ({                                                       \
    int P_ = (wc * 32 + (nf) * 16 + l15) * 128 + ((ks) * 4 + quad) * 16;       \
    int L_ = P_ ^ (((P_ >> 7) & 7) << 4);                                      \
    *(const short8*)(bbO + (L_ >> 1)); })

#define PHASE_MFMA_O(MH)                                                       \
    __builtin_amdgcn_s_setprio(1);                                             \
    _Pragma("unroll")                                                          \
    for (int j2 = 0; j2 < 4; ++j2)                                             \
        _Pragma("unroll")                                                      \
        for (int nf2 = 0; nf2 < 2; ++nf2)                                      \
            acc[(MH) * 4 + j2][nf2] = __builtin_amdgcn_mfma_f32_16x16x32_bf16( \
                af[j2], bf[nf2], acc[(MH) * 4 + j2][nf2], 0, 0, 0);            \
    __builtin_amdgcn_s_setprio(0);

    STAGE_A(0, 0, 0); STAGE_B(0, 0, 0);
    STAGE_A(0, 0, 1); STAGE_B(0, 0, 1);
    STAGE_A(0, 0, 2); STAGE_A(0, 0, 3);

    for (int t = 0; t < 16; ++t) {
        const int pp2 = t & 1;
        const u16* ab  = &Ls[pp2 * 24576 + wr * 8192];
        const u16* bbO = &Ls[pp2 * 24576 + 16384];
        const int dn = pp2 ^ 1;
        const bool more = (t + 1) < 16;
        short8 af[4], bf[2];
        if (more) { STAGE_A(t + 1, dn, 0); STAGE_B(t + 1, dn, 0); }
        if (more) asm volatile("s_waitcnt vmcnt(2)" ::: "memory");
        else      asm volatile("s_waitcnt vmcnt(0)" ::: "memory");
        __builtin_amdgcn_s_barrier();
        __builtin_amdgcn_sched_barrier(0);
        #pragma unroll
        for (int nf = 0; nf < 2; ++nf) bf[nf] = LDB8O(nf, 0);
        #pragma unroll
        for (int j = 0; j < 4; ++j) af[j] = LDA8O(j, 0);
        PHASE_MFMA_O(0)
        __builtin_amdgcn_s_barrier();
        #pragma unroll
        for (int j = 0; j < 4; ++j) af[j] = LDA8O(4 + j, 0);
        if (more) { STAGE_A(t + 1, dn, 1); STAGE_B(t + 1, dn, 1); }
        __builtin_amdgcn_s_barrier();
        __builtin_amdgcn_sched_barrier(0);
        PHASE_MFMA_O(1)
        __builtin_amdgcn_s_barrier();
        #pragma unroll
        for (int nf = 0; nf < 2; ++nf) bf[nf] = LDB8O(nf, 1);
        #pragma unroll
        for (int j = 0; j < 4; ++j) af[j] = LDA8O(j, 1);
        if (more) STAGE_A(t + 1, dn, 2);
        __builtin_amdgcn_s_barrier();
        __builtin_amdgcn_sched_barrier(0);
        PHASE_MFMA_O(0)
        __builtin_amdgcn_s_barrier();
        #pragma unroll
        for (int j = 0; j < 4; ++j) af[j] = LDA8O(4 + j, 1);
        if (more) STAGE_A(t + 1, dn, 3);
        __builtin_amdgcn_s_barrier();
        __builtin_amdgcn_sched_barrier(0);
        PHASE_MFMA_O(1)
        __builtin_amdgcn_s_barrier();
    }

    #pragma unroll
    for (int mf = 0; mf < 8; ++mf)
        #pragma unroll
        for (int r = 0; r < 4; ++r) {
            size_t rowg = (size_t)(m0 + wr * 128 + mf * 16 + quad * 4 + r);
            #pragma unroll
            for (int nf = 0; nf < 2; ++nf) {
                int colg = n0 + wc * 32 + nf * 16 + l15;
                outO[rowg * MODEL_DIM + colg] = acc[mf][nf][r] + bo[colg];
            }
        }
#undef STAGE_A
#undef STAGE_B
#undef LDA8O
#undef LDB8O
#undef PHASE_MFMA_O
}

// ------------------------------------------------------- flash attention (causal)
// Verified R15: 512 thr = 8 waves; wave owns 16 q-rows -> 16 waves/CU at
// 2 blocks/CU. Pair-balancing; T14 dbuf pipeline; T13 defer-max; T5 setprio;
// exp2-domain softmax.
__global__ __launch_bounds__(512, 2) void attn_k(const u16* __restrict__ Qb,
                                                 const u16* __restrict__ Kb,
                                                 const u32* __restrict__ VT32,
                                                 u16* __restrict__ Ob) {
    __shared__ __align__(16) u16 Ks[2][64 * 64];   // [key][dim], chunk-XOR swizzle
    __shared__ __align__(16) u16 Vs[2][64 * 64];   // [d][key],   chunk-XOR swizzle
    __shared__ __align__(16) u16 Pl[8 * 16 * 72];  // per-wave P^T [q][key], pad 8
    const int tid  = threadIdx.x;
    const int wave = tid >> 6, lane = tid & 63;
    const int l15  = lane & 15, quad = lane >> 4;
    const int j = blockIdx.x;                      // 0..7 pair index
    const int h = blockIdx.y, b = blockIdx.z;
    u16* pw = &Pl[wave * 16 * 72];

    // staging geometry: 512 thr x 16B = one full 64x64 bf16 tile per pass
    const int key0 = tid >> 3;                     // 0..63
    const int c8   = (tid & 7) * 8;                // u16 units
    const int c4   = (tid & 7) * 4;                // u32 units (VT rows)
    const int lko  = key0 * 64 + (((tid & 7) ^ (key0 & 7)) * 8);   // LDS dst
    const u16* kgp = Kb + (size_t)(b * SEQ) * MODEL_DIM + h * HDIM;
    const u32* vgp = VT32 + (size_t)((b * NHEAD + h) * HDIM) * (SEQ / 2);

    int bufc = 0;                                  // buffer parity, spans passes
    for (int pp = 0; pp < 2; ++pp) {
        const int qt = pp ? j : 15 - j;            // heavy tile first
        const int q0 = qt * 128;
        const int qbase = q0 + wave * 16;          // this wave's 16 q-rows

        // Q B-frags (n=q=l15, k=dim=quad*8+jj), pre-scaled 0.125*log2e
        short8 qfr[2];
        for (int ks = 0; ks < 2; ++ks)
            qfr[ks] = *(const short8*)(Qb
                + (size_t)(b * SEQ + qbase + l15) * MODEL_DIM
                + h * HDIM + ks * 32 + quad * 8);

        float m_i = -1e30f, l_i = 0.f;
        f32x4 o_acc[4] = {};                       // [dt]

        const int nkt = (q0 + 128) >> 6;
        // prologue prefetch (kt = 0): 1 uint4 each for K and V^T
        uint4 kr0 = *(const uint4*)(kgp + (size_t)key0 * MODEL_DIM + c8);
        uint4 vr0 = *(const uint4*)(vgp + (size_t)key0 * (SEQ / 2) + c4);

        for (int kt = 0; kt < nkt; ++kt) {
            const int k0 = kt * 64;
            u16* ksb = Ks[bufc];
            u16* vsb = Vs[bufc];
            *(uint4*)(&ksb[lko]) = kr0;            // drain prefetched tile -> LDS
            *(uint4*)(&vsb[lko]) = vr0;
            __syncthreads();                       // single barrier per iter

            if (kt + 1 < nkt) {                    // prefetch next tile (hidden
                const int kn = k0 + 64;            //  under this tile's compute)
                kr0 = *(const uint4*)(kgp + (size_t)(kn + key0) * MODEL_DIM + c8);
                vr0 = *(const uint4*)(vgp + (size_t)key0 * (SEQ / 2) + (kn >> 1) + c4);
            }

            if (k0 <= qbase + 15) {                // wave has live rows this tile
                // S^T = K Q^T
                f32x4 s[4] = {};
                for (int ks = 0; ks < 2; ++ks) {
                    short8 kfr[4];
                    for (int kf = 0; kf < 4; ++kf)
                        kfr[kf] = *(const short8*)(&ksb[(kf * 16 + l15) * 64
                                      + (((ks * 4 + quad) ^ (l15 & 7)) * 8)]);
                    __builtin_amdgcn_s_setprio(1);
                    for (int kf = 0; kf < 4; ++kf)
                        s[kf] = __builtin_amdgcn_mfma_f32_16x16x32_bf16(
                                    kfr[kf], qfr[ks], s[kf], 0, 0, 0);
                    __builtin_amdgcn_s_setprio(0);
                }
                const int qg = qbase + l15;
                if (k0 + 63 > qbase) {             // diagonal tile: apply mask
                    for (int kf = 0; kf < 4; ++kf)
                        for (int r = 0; r < 4; ++r)
                            if (k0 + kf * 16 + quad * 4 + r > qg)
                                s[kf][r] = -1e30f;
                }
                // max via fmaxf triples (v_max3 fusion)
                float t0 = fmaxf(fmaxf(s[0][0], s[0][1]), fmaxf(s[0][2], s[0][3]));
                float t1 = fmaxf(fmaxf(s[1][0], s[1][1]), fmaxf(s[1][2], s[1][3]));
                float t2 = fmaxf(fmaxf(s[2][0], s[2][1]), fmaxf(s[2][2], s[2][3]));
                float t3 = fmaxf(fmaxf(s[3][0], s[3][1]), fmaxf(s[3][2], s[3][3]));
                float rmax = fmaxf(fmaxf(t0, t1), fmaxf(t2, t3));
                rmax = fmaxf(rmax, __shfl_xor(rmax, 16, 64));
                rmax = fmaxf(rmax, __shfl_xor(rmax, 32, 64));
                // T13 defer-max: skip rescale unless some row grew > +8
                if (!__all(rmax <= m_i + 8.0f)) {
                    float mn = fmaxf(m_i, rmax);
                    float alpha = exp2a(m_i - mn);
                    m_i = mn;
                    l_i *= alpha;
                    for (int dt = 0; dt < 4; ++dt)
                        for (int r = 0; r < 4; ++r) o_acc[dt][r] *= alpha;
                }
                float psum = 0.f;
                for (int kf = 0; kf < 4; ++kf)
                    for (int r = 0; r < 4; ++r) {
                        float p = exp2a(s[kf][r] - m_i);
                        s[kf][r] = p;
                        psum += p;
                    }
                psum += __shfl_xor(psum, 16, 64);
                psum += __shfl_xor(psum, 32, 64);
                l_i += psum;
                for (int kf = 0; kf < 4; ++kf) {   // P^T -> LDS (uint2)
                    uint2 w;
                    w.x = cvtpk(s[kf][0], s[kf][1]);
                    w.y = cvtpk(s[kf][2], s[kf][3]);
                    *(uint2*)(&pw[l15 * 72 + kf * 16 + quad * 4]) = w;
                }
                // O^T += V^T P^T
                for (int ks = 0; ks < 2; ++ks) {
                    short8 pfr, vfr[4];
                    pfr = *(const short8*)(&pw[l15 * 72 + ks * 32 + quad * 8]);
                    for (int dt = 0; dt < 4; ++dt)
                        vfr[dt] = *(const short8*)(&vsb[(dt * 16 + l15) * 64
                                      + (((ks * 4 + quad) ^ (l15 & 7)) * 8)]);
                    __builtin_amdgcn_s_setprio(1);
                    for (int dt = 0; dt < 4; ++dt)
                        o_acc[dt] = __builtin_amdgcn_mfma_f32_16x16x32_bf16(
                                        vfr[dt], pfr, o_acc[dt], 0, 0, 0);
                    __builtin_amdgcn_s_setprio(0);
                }
            }
            bufc ^= 1;
        }

        // O^T C-layout: q = l15, d = quad*4+r (within dt)
        {
            float rl = 1.f / l_i;
            int q = qbase + l15;
            for (int dt = 0; dt < 4; ++dt) {
                uint2 w;
                w.x = cvtpk(o_acc[dt][0] * rl, o_acc[dt][1] * rl);
                w.y = cvtpk(o_acc[dt][2] * rl, o_acc[dt][3] * rl);
                *(uint2*)(&Ob[(size_t)(b * SEQ + q) * MODEL_DIM
                              + h * HDIM + dt * 16 + quad * 4]) = w;
            }
        }
    }
}

// --------------------------------------------------------------------- launcher
extern "C" void kernel_launch(void* const* d_in, const int* in_sizes, int n_in,
                              void* d_out, int out_size, void* d_ws, size_t ws_size,
                              hipStream_t stream) {
    const float* X  = (const float*)d_in[0];
    const float* Wq = (const float*)d_in[1];
    const float* bq = (const float*)d_in[2];
    const float* Wk = (const float*)d_in[3];
    const float* bk = (const float*)d_in[4];
    const float* Wv = (const float*)d_in[5];
    const float* bv = (const float*)d_in[6];
    const float* Wo = (const float*)d_in[7];
    const float* bo = (const float*)d_in[8];
    float* out = (float*)d_out;

    // ws: [Xb/Ob 16.78M][Wt 8.39M][Qb 16.78M][Kb 16.78M][unused][VT 16.78M]
    char* ws = (char*)d_ws;
    u16* Xb   = (u16*)ws;                       // aliased by Ob after QKV GEMM
    u16* Ob   = (u16*)ws;
    u16* Wt   = (u16*)(ws + 16777216);
    u16* Qb   = (u16*)(ws + 25165824);
    u16* Kb   = (u16*)(ws + 41943040);
    u32* VT32 = (u32*)(ws + 75497472);

    prep_k<<<dim3(12288), dim3(256), 0, stream>>>(X, Xb, Wq, Wk, Wv, Wo, Wt);
    gemm256qkv_k<<<dim3(32, 24), dim3(512), 0, stream>>>(Xb, Wt, Qb, Kb, VT32,
                                                         bq, bk, bv);
    attn_k<<<dim3(8, 16, 4), dim3(512), 0, stream>>>(Qb, Kb, VT32, Ob);
    gemm256o_k<<<dim3(32, 8), dim3(512), 0, stream>>>(Ob, Wt, out, bo);
}